// Round 3
// baseline (1379.098 us; speedup 1.0000x reference)
//
#include <hip/hip_runtime.h>
#include <cstdint>

#define EPS 1e-5f
#define PADW 258          // W+2
#define PADROWS 33540     // (H+2)*(W+2) = 130*258
#define NPIX 32768        // H*W per batch

typedef __attribute__((ext_vector_type(8))) short bf16x8;
typedef __attribute__((ext_vector_type(4))) float f32x4;

__device__ __forceinline__ ushort f2bf(float f) {
  union { float f; uint32_t u; } v; v.f = f;
  uint32_t r = v.u + 0x7fffu + ((v.u >> 16) & 1u);  // round-to-nearest-even
  return (ushort)(r >> 16);
}
__device__ __forceinline__ float bf2f(ushort h) {
  union { uint32_t u; float f; } v; v.u = ((uint32_t)h) << 16;
  return v.f;
}
__device__ __forceinline__ void gload_lds16(const void* g, void* lds) {
  __builtin_amdgcn_global_load_lds((__attribute__((address_space(1))) void*)g,
                                   (__attribute__((address_space(3))) void*)lds,
                                   16, 0, 0);
}

// ---------------------------------------------------------------------------
// Unified MFMA GEMM (three 1x1 convs). Round 6: coalesced+swizzled staging.
//   A/B LDS layout [row 128][oct 4][8ci], oct XOR-swizzled by ((row>>1)&3):
//   staging reads 16 rows x 64B contiguous per instr (16 lines, was 64),
//   frag ds_read_b128 conflict-free (proven pattern from conv R2).
// ---------------------------------------------------------------------------
template <int BMODE, int OMODE>
__global__ __launch_bounds__(256) void mfma_gemm(
    const ushort* __restrict__ A, const ushort* __restrict__ B,
    const float* __restrict__ bn, void* __restrict__ OutV,
    int M, int K, int pitchB, int ciB, long strideB, int pitchO, long strideO) {
  const int lane = threadIdx.x & 63;
  const int wave = threadIdx.x >> 6;
  const int wm = (wave & 1) * 64;
  const int wn = (wave >> 1) * 64;
  const int m0 = blockIdx.y * 128;
  const int n0 = blockIdx.x * 128;
  const int z  = blockIdx.z;
  B += (size_t)z * strideB;

  const int h = n0 >> 8, w0 = n0 & 255;
  long prowB;
  if (BMODE == 0) prowB = n0;
  else            prowB = (long)(h + 1) * PADW + (w0 + 1);

  __shared__ __align__(16) ushort Asl[4 * 128 * 8];
  __shared__ __align__(16) ushort Bsl[4 * 128 * 8];

  f32x4 acc[4][4];
#pragma unroll
  for (int mt = 0; mt < 4; ++mt)
#pragma unroll
    for (int nt = 0; nt < 4; ++nt) acc[mt][nt] = (f32x4){0.f, 0.f, 0.f, 0.f};

  for (int k0 = 0; k0 < K; k0 += 32) {
#pragma unroll
    for (int i = 0; i < 2; ++i) {
      int c = (wave * 2 + i) * 64 + lane;       // chunk [0,512)
      int mm = c >> 2, g = (c & 3) ^ ((mm >> 1) & 3);
      gload_lds16(A + (size_t)(m0 + mm) * K + (k0 + g * 8), Asl + c * 8);
    }
    long rowb; int cib;
    if (BMODE == 2) {
      int tap = k0 >> 10;
      int dy = tap / 3 - 1, dx = tap % 3 - 1;
      rowb = prowB + dy * PADW + dx;
      cib  = k0 & 1023;
    } else {
      rowb = prowB;
      cib  = ciB + k0;
    }
#pragma unroll
    for (int i = 0; i < 2; ++i) {
      int c = (wave * 2 + i) * 64 + lane;
      int nn = c >> 2, g = (c & 3) ^ ((nn >> 1) & 3);
      gload_lds16(B + (size_t)(rowb + nn) * pitchB + cib + g * 8, Bsl + c * 8);
    }
    __syncthreads();
    bf16x8 af[4], bfr[4];
#pragma unroll
    for (int t = 0; t < 4; ++t) {
      int ks = lane >> 4;
      int ma = wm + t * 16 + (lane & 15);
      int nb = wn + t * 16 + (lane & 15);
      af[t]  = *(const bf16x8*)(Asl + (ma * 4 + (ks ^ ((ma >> 1) & 3))) * 8);
      bfr[t] = *(const bf16x8*)(Bsl + (nb * 4 + (ks ^ ((nb >> 1) & 3))) * 8);
    }
#pragma unroll
    for (int mt = 0; mt < 4; ++mt)
#pragma unroll
      for (int nt = 0; nt < 4; ++nt)
        acc[mt][nt] = __builtin_amdgcn_mfma_f32_16x16x32_bf16(af[mt], bfr[nt], acc[mt][nt], 0, 0, 0);
    __syncthreads();
  }

  const int q4 = lane >> 4, col = lane & 15;
  float scv[16], bov[16];
#pragma unroll
  for (int mt = 0; mt < 4; ++mt)
#pragma unroll
    for (int r = 0; r < 4; ++r) {
      int m = m0 + wm + mt * 16 + q4 * 4 + r;
      float s = bn[m] * rsqrtf(bn[3 * M + m] + EPS);
      scv[mt * 4 + r] = s;
      bov[mt * 4 + r] = bn[M + m] - bn[2 * M + m] * s;
    }
  if (OMODE == 2) {
    float* Outf = (float*)OutV + (size_t)z * strideO;
#pragma unroll
    for (int mt = 0; mt < 4; ++mt)
#pragma unroll
      for (int r = 0; r < 4; ++r) {
        int m = m0 + wm + mt * 16 + q4 * 4 + r;
        float* rowp = Outf + (size_t)m * NPIX + n0 + wn;
#pragma unroll
        for (int nt = 0; nt < 4; ++nt)
          rowp[nt * 16 + col] = fmaxf(acc[mt][nt][r] * scv[mt * 4 + r] + bov[mt * 4 + r], 0.f);
      }
  } else {
    ushort* Outh = (ushort*)OutV + (size_t)z * strideO;
    long prowO = (OMODE == 0) ? (long)n0 : ((long)(h + 1) * PADW + (w0 + 1));
#pragma unroll
    for (int nt = 0; nt < 4; ++nt) {
      long row = prowO + wn + nt * 16 + col;
      ushort* p = Outh + (size_t)row * pitchO + m0 + wm;
#pragma unroll
      for (int mt = 0; mt < 4; ++mt) {
        ushort4 pk;
        pk.x = f2bf(fmaxf(acc[mt][nt][0] * scv[mt * 4 + 0] + bov[mt * 4 + 0], 0.f));
        pk.y = f2bf(fmaxf(acc[mt][nt][1] * scv[mt * 4 + 1] + bov[mt * 4 + 1], 0.f));
        pk.z = f2bf(fmaxf(acc[mt][nt][2] * scv[mt * 4 + 2] + bov[mt * 4 + 2], 0.f));
        pk.w = f2bf(fmaxf(acc[mt][nt][3] * scv[mt * 4 + 3] + bov[mt * 4 + 3], 0.f));
        *(ushort4*)(p + mt * 16 + q4 * 4) = pk;
      }
    }
  }
}

// ---------------------------------------------------------------------------
// Conv3x3 halo-LDS implicit GEMM, round 6:
//   * bfr ping-pong: tap t+1's 4 ds_read_b128 issued before tap t's MFMA
//     cluster -> LDS latency hidden (was exposed 9x per iter).
//   * A-prologue for iter it+1 folded into taps 6-8 of iter it (each ring
//     slot refilled right after its last read) -> no vmcnt(0) in the loop.
//   * __syncthreads replaced by s_waitcnt vmcnt(12) + raw s_barrier:
//     staging + refills guaranteed retired, the 12 next-iter A loads stay
//     in flight across the barrier (T4 counted-vmcnt).
// ---------------------------------------------------------------------------
#define PXS  130          // pixels per halo row (128 + 2 halo)
#define ROWC (PXS * 4)    // 520 chunks per row
#define BUFC (3 * ROWC)   // 1560 chunks per buffer (24,960 B)
__global__ __launch_bounds__(256, 3) void conv3x3_mfma(
    const ushort* __restrict__ W2, const ushort* __restrict__ cat,
    const float* __restrict__ bn, float* __restrict__ out) {
  const int tid  = threadIdx.x;
  const int lane = tid & 63;
  const int wave = tid >> 6;
  const int wm = (wave & 1) * 64;
  const int wn = (wave >> 1) * 64;
  const int m0 = (blockIdx.x & 3) * 128;
  const int n0 = (blockIdx.x >> 2) * 128;
  const int z  = blockIdx.z;
  const int h = n0 >> 8, w0 = n0 & 255;
  const long prow0 = (long)(h + 1) * PADW + (w0 + 1);
  const ushort* Bz = cat + (size_t)z * PADROWS * 1024;

  __shared__ __align__(16) ushort halo[2 * BUFC * 8];  // 49,920 B

  f32x4 acc[4][4];
#pragma unroll
  for (int mt = 0; mt < 4; ++mt)
#pragma unroll
    for (int nt = 0; nt < 4; ++nt) acc[mt][nt] = (f32x4){0.f, 0.f, 0.f, 0.f};

  // Per-thread staging source offsets (ushort units, ci-independent).
  // LDS slot chunk c = (r*130 + p)*4 + o_slot holds GLOBAL octet
  // o_g = o_slot ^ ((p>>1)&3)  (pre-swizzled source, linear LDS dest).
  long offs[7];
#pragma unroll
  for (int s = 0; s < 7; ++s) {
    int c = s * 256 + tid;
    if (c < BUFC) {
      int o_slot = c & 3;
      int q = c >> 2;
      int p = q % PXS;
      int r = q / PXS;
      int o_g = o_slot ^ ((p >> 1) & 3);
      offs[s] = ((prow0 + (long)(r - 1) * PADW + (p - 1)) << 10) + o_g * 8;
    } else {
      offs[s] = -1;
    }
  }

  auto stage = [&](int buf, int ci0n) {
#pragma unroll
    for (int s = 0; s < 7; ++s)
      if (offs[s] >= 0)
        gload_lds16(Bz + offs[s] + ci0n,
                    halo + ((size_t)buf * BUFC + s * 256 + wave * 64) * 8);
  };

  // Per-lane A base inside one (chunk,tap) 512x32 block:
  //   co = m0 + wm + mt*16 + (lane&15), octet = lane>>4.
  const ushort* Alane = W2 + (size_t)(m0 + wm + (lane & 15)) * 32 + (lane >> 4) * 8;

  // Precompute swizzled halo byte offsets for the 12 (nt,dx) read positions.
  const int p0  = wn + (lane & 15);
  const int oct = lane >> 4;
  int hoff[12];
#pragma unroll
  for (int nt = 0; nt < 4; ++nt)
#pragma unroll
    for (int dx = 0; dx < 3; ++dx) {
      int p = p0 + nt * 16 + dx;
      hoff[nt * 3 + dx] = (p * 4 + (oct ^ ((p >> 1) & 3))) * 16;  // bytes
    }

  stage(0, 0);
  // Iter-0 A prologue (issued after staging; allowed outstanding at barrier).
  bf16x8 af[3][4];
#pragma unroll
  for (int t = 0; t < 3; ++t)
#pragma unroll
    for (int mt = 0; mt < 4; ++mt)
      af[t][mt] = *(const bf16x8*)(Alane + (size_t)t * 16384 + mt * 512);

  asm volatile("s_waitcnt vmcnt(12)" ::: "memory");
  __builtin_amdgcn_sched_barrier(0);
  __builtin_amdgcn_s_barrier();
  __builtin_amdgcn_sched_barrier(0);

  for (int it = 0; it < 32; ++it) {
    const ushort* Ait = Alane + (size_t)it * (9 * 16384);
    const ushort* An  = (it < 31) ? Ait + (size_t)(9 * 16384) : Ait;
    if (it < 31) stage((it + 1) & 1, (it + 1) * 32);
    __builtin_amdgcn_sched_barrier(0);

    const char* hb0 = (const char*)(halo + (size_t)(it & 1) * BUFC * 8);
    bf16x8 bfr[2][4];
#pragma unroll
    for (int nt = 0; nt < 4; ++nt)
      bfr[0][nt] = *(const bf16x8*)(hb0 + hoff[nt * 3]);

#pragma unroll
    for (int t = 0; t < 9; ++t) {
      const int slot = t % 3;
      if (t < 8) {  // prefetch next tap's B frags into the other bfr set
        const int r = (t + 1) / 3, dx = (t + 1) % 3;
#pragma unroll
        for (int nt = 0; nt < 4; ++nt)
          bfr[(t + 1) & 1][nt] = *(const bf16x8*)(hb0 + r * (ROWC * 16) + hoff[nt * 3 + dx]);
      }
      __builtin_amdgcn_s_setprio(1);
#pragma unroll
      for (int nt = 0; nt < 4; ++nt)
#pragma unroll
        for (int mt = 0; mt < 4; ++mt)
          acc[mt][nt] = __builtin_amdgcn_mfma_f32_16x16x32_bf16(af[slot][mt], bfr[t & 1][nt], acc[mt][nt], 0, 0, 0);
      __builtin_amdgcn_s_setprio(0);
      if (t < 6) {  // ring refill: tap t+3 of this iter
#pragma unroll
        for (int mt = 0; mt < 4; ++mt)
          af[slot][mt] = *(const bf16x8*)(Ait + (size_t)(t + 3) * 16384 + mt * 512);
      } else {      // prologue for next iter: tap t-6 (same ring slot)
#pragma unroll
        for (int mt = 0; mt < 4; ++mt)
          af[slot][mt] = *(const bf16x8*)(An + (size_t)(t - 6) * 16384 + mt * 512);
      }
    }
    // Counted drain: staging+refills retired, 12 prologue loads may remain.
    asm volatile("s_waitcnt vmcnt(12)" ::: "memory");
    __builtin_amdgcn_sched_barrier(0);
    __builtin_amdgcn_s_barrier();
    __builtin_amdgcn_sched_barrier(0);
  }

  // Epilogue: BN + ReLU, fp32 NCHW out.
  const int q4 = lane >> 4, col = lane & 15;
  float* Outf = out + (size_t)z * 512 * NPIX;
#pragma unroll
  for (int mt = 0; mt < 4; ++mt)
#pragma unroll
    for (int r = 0; r < 4; ++r) {
      int m = m0 + wm + mt * 16 + q4 * 4 + r;
      float s  = bn[m] * rsqrtf(bn[3 * 512 + m] + EPS);
      float bo = bn[512 + m] - bn[2 * 512 + m] * s;
      float* rowp = Outf + (size_t)m * NPIX + n0 + wn;
#pragma unroll
      for (int nt = 0; nt < 4; ++nt)
        rowp[nt * 16 + col] = fmaxf(acc[mt][nt][r] * s + bo, 0.f);
    }
}

// ---------------------------------------------------------------------------
// Tiny GEMM for the k/v path (fp32, negligible cost)
// ---------------------------------------------------------------------------
__global__ __launch_bounds__(64) void small_gemm_kernel(
    const float* __restrict__ Wm, const float* __restrict__ X,
    const float* __restrict__ bn, float* __restrict__ Y,
    int CO, int CI, int KC) {
  int co = blockIdx.x, b = blockIdx.y, kc = threadIdx.x;
  if (kc >= KC) return;
  const float* Xb = X + (size_t)b * CI * KC;
  float acc = 0.f;
  for (int c = 0; c < CI; ++c) acc += Wm[(size_t)co * CI + c] * Xb[(size_t)c * KC + kc];
  float s  = bn[co] * rsqrtf(bn[3 * CO + co] + EPS);
  float bs = bn[CO + co] - bn[2 * CO + co] * s;
  Y[((size_t)b * CO + co) * KC + kc] = fmaxf(acc * s + bs, 0.f);
}

// ---------------------------------------------------------------------------
// Attention: qT/ctxT in [pixel][256ch] bf16; k/v fp32 staged in LDS.
// ---------------------------------------------------------------------------
__global__ __launch_bounds__(256) void attention_kernel(
    const ushort* __restrict__ qT, const float* __restrict__ Kp,
    const float* __restrict__ Vp, ushort* __restrict__ ctxT) {
  int b = blockIdx.y;
  int pix = blockIdx.x * 256 + threadIdx.x;
  __shared__ float ks[256][19], vs[256][19];
  for (int idx = threadIdx.x; idx < 256 * 19; idx += 256) {
    int c = idx / 19, kk = idx % 19;
    ks[c][kk] = Kp[((size_t)b * 256 + c) * 19 + kk];
    vs[c][kk] = Vp[((size_t)b * 256 + c) * 19 + kk];
  }
  __syncthreads();

  const ushort* qrow = qT + ((size_t)b * NPIX + pix) * 256;
  float sim[19];
#pragma unroll
  for (int kk = 0; kk < 19; ++kk) sim[kk] = 0.f;
  for (int c0 = 0; c0 < 256; c0 += 8) {
    uint4 raw = *(const uint4*)(qrow + c0);
    float qf[8] = {bf2f((ushort)(raw.x & 0xffff)), bf2f((ushort)(raw.x >> 16)),
                   bf2f((ushort)(raw.y & 0xffff)), bf2f((ushort)(raw.y >> 16)),
                   bf2f((ushort)(raw.z & 0xffff)), bf2f((ushort)(raw.z >> 16)),
                   bf2f((ushort)(raw.w & 0xffff)), bf2f((ushort)(raw.w >> 16))};
#pragma unroll
    for (int j = 0; j < 8; ++j)
#pragma unroll
      for (int kk = 0; kk < 19; ++kk) sim[kk] += qf[j] * ks[c0 + j][kk];
  }
  const float scale = 0.0625f;
  float mx = -1e30f;
#pragma unroll
  for (int kk = 0; kk < 19; ++kk) { sim[kk] *= scale; mx = fmaxf(mx, sim[kk]); }
  float denom = 0.f;
#pragma unroll
  for (int kk = 0; kk < 19; ++kk) { sim[kk] = __expf(sim[kk] - mx); denom += sim[kk]; }
  float inv = 1.f / denom;
#pragma unroll
  for (int kk = 0; kk < 19; ++kk) sim[kk] *= inv;

  ushort* crow = ctxT + ((size_t)b * NPIX + pix) * 256;
  for (int c0 = 0; c0 < 256; c0 += 8) {
    uint32_t o[4];
#pragma unroll
    for (int j = 0; j < 4; ++j) {
      float v0 = 0.f, v1 = 0.f;
#pragma unroll
      for (int kk = 0; kk < 19; ++kk) {
        v0 += sim[kk] * vs[c0 + j * 2][kk];
        v1 += sim[kk] * vs[c0 + j * 2 + 1][kk];
      }
      o[j] = (uint32_t)f2bf(v0) | ((uint32_t)f2bf(v1) << 16);
    }
    *(uint4*)(crow + c0) = make_uint4(o[0], o[1], o[2], o[3]);
  }
}

// ---------------------------------------------------------------------------
// Transpose x (fp32 [b][512][HW]) into cat_pad (bf16 [b][p][1024], ch 512..1023)
// ---------------------------------------------------------------------------
__global__ __launch_bounds__(256) void transpose_x_kernel(
    const float* __restrict__ x, ushort* __restrict__ cat) {
  int b = blockIdx.z, ci0 = blockIdx.y * 64, n0 = blockIdx.x * 64;
  __shared__ float t[64][65];
  const float* xb = x + ((size_t)b * 512 + ci0) * NPIX + n0;
  for (int i = 0; i < 16; ++i) {
    int idx = i * 256 + threadIdx.x;
    int c = idx >> 6, w = idx & 63;
    t[c][w] = xb[(size_t)c * NPIX + w];
  }
  __syncthreads();
  int h = n0 >> 8, w0 = n0 & 255;
  size_t pbase = ((size_t)b * PADROWS + (size_t)(h + 1) * PADW + (w0 + 1)) * 1024 + 512 + ci0;
  for (int i = 0; i < 16; ++i) {
    int idx = i * 256 + threadIdx.x;
    int n = idx >> 6, c = idx & 63;
    cat[pbase + (size_t)n * 1024 + c] = f2bf(t[c][n]);
  }
}

// ---------------------------------------------------------------------------
// Weight conversions
// ---------------------------------------------------------------------------
__global__ void convert_w_kernel(const float* __restrict__ in, ushort* __restrict__ out, int n) {
  int i = blockIdx.x * 256 + threadIdx.x;
  if (i < n) out[i] = f2bf(in[i]);
}
// Repack wbot (co,ci,ky,kx) fp32 -> W2 bf16 [ci_chunk 32][tap 9][co 512][32 ci]
__global__ void repack_conv_w_kernel(const float* __restrict__ wbot, ushort* __restrict__ Wrb) {
  int idx = blockIdx.x * 256 + threadIdx.x;
  if (idx >= 512 * 9216) return;
  int ci_in = idx & 31;
  int r  = idx >> 5;
  int co = r & 511;
  int tt = r >> 9;
  int t = tt % 9, chunk = tt / 9;
  Wrb[idx] = f2bf(wbot[((size_t)co * 1024 + chunk * 32 + ci_in) * 9 + t]);
}

// ---------------------------------------------------------------------------
extern "C" void kernel_launch(void* const* d_in, const int* in_sizes, int n_in,
                              void* d_out, int out_size, void* d_ws, size_t ws_size,
                              hipStream_t stream) {
  const float* x     = (const float*)d_in[0];
  const float* proxy = (const float*)d_in[1];
  const float* wq1   = (const float*)d_in[2];
  const float* bnq1  = (const float*)d_in[3];
  const float* wq2   = (const float*)d_in[4];
  const float* bnq2  = (const float*)d_in[5];
  const float* wk1   = (const float*)d_in[6];
  const float* bnk1  = (const float*)d_in[7];
  const float* wk2   = (const float*)d_in[8];
  const float* bnk2  = (const float*)d_in[9];
  const float* wv    = (const float*)d_in[10];
  const float* bnv   = (const float*)d_in[11];
  const float* wout  = (const float*)d_in[12];
  const float* bnout = (const float*)d_in[13];
  const float* wbot  = (const float*)d_in[14];
  const float* bnbot = (const float*)d_in[15];
  float* out = (float*)d_out;

  const int B = 2, C = 512, CK = 256, KC = 19;
  char* ws = (char*)d_ws;
  const size_t catBytes = (size_t)B * PADROWS * 1024 * 2;  // 137,379,840
  ushort* cat  = (ushort*)ws;
  ushort* bufA = (ushort*)(ws + 137379840);                // q1T, later ctxT (32 MiB)
  ushort* bufB = (ushort*)(ws + 137379840 + 33554432);     // qT (32 MiB)
  ushort* Wrb  = (ushort*)(ws + 204488704);                // 9 MiB
  ushort* wq1b = (ushort*)(ws + 213925888);
  ushort* wq2b = (ushort*)(ws + 214188032);
  ushort* woutb= (ushort*)(ws + 214319104);
  float*  k1   = (float*)(ws + 214581248);
  float*  k2   = k1 + (size_t)B * CK * KC;
  float*  vv   = k2 + (size_t)B * CK * KC;

  hipMemsetAsync(cat, 0, catBytes, stream);

  convert_w_kernel<<<(CK * C + 255) / 256, 256, 0, stream>>>(wq1, wq1b, CK * C);
  convert_w_kernel<<<(CK * CK + 255) / 256, 256, 0, stream>>>(wq2, wq2b, CK * CK);
  convert_w_kernel<<<(C * CK + 255) / 256, 256, 0, stream>>>(wout, woutb, C * CK);
  repack_conv_w_kernel<<<(512 * 9216 + 255) / 256, 256, 0, stream>>>(wbot, Wrb);

  small_gemm_kernel<<<dim3(CK, B), 64, 0, stream>>>(wk1, proxy, bnk1, k1, CK, C, KC);
  small_gemm_kernel<<<dim3(CK, B), 64, 0, stream>>>(wk2, k1, bnk2, k2, CK, CK, KC);
  small_gemm_kernel<<<dim3(CK, B), 64, 0, stream>>>(wv, proxy, bnv, vv, CK, C, KC);

  transpose_x_kernel<<<dim3(NPIX / 64, 8, B), 256, 0, stream>>>(x, cat);

  const long padStride = (long)PADROWS * 1024;
  const long nckStride = (long)NPIX * 256;

  mfma_gemm<1, 0><<<dim3(NPIX / 128, 2, B), 256, 0, stream>>>(
      wq1b, cat, bnq1, bufA, 256, 512, 1024, 512, padStride, 256, nckStride);
  mfma_gemm<0, 0><<<dim3(NPIX / 128, 2, B), 256, 0, stream>>>(
      wq2b, bufA, bnq2, bufB, 256, 256, 256, 0, nckStride, 256, nckStride);

  attention_kernel<<<dim3(NPIX / 256, B), 256, 0, stream>>>(bufB, k2, vv, bufA);

  mfma_gemm<0, 1><<<dim3(NPIX / 128, 4, B), 256, 0, stream>>>(
      woutb, bufA, bnout, cat, 512, 256, 256, 0, nckStride, 1024, padStride);

  // conv3x3: halo-LDS implicit GEMM; grid.x = n_tile*4 + m_tile (XCD swizzle)
  conv3x3_mfma<<<dim3((NPIX / 128) * 4, 1, B), 256, 0, stream>>>(Wrb, cat, bnbot, out);
}

// Round 4
// 1276.366 us; speedup vs baseline: 1.0805x; 1.0805x over previous
//
#include <hip/hip_runtime.h>
#include <cstdint>

#define EPS 1e-5f
#define PADW 258          // W+2
#define PADROWS 33540     // (H+2)*(W+2) = 130*258
#define NPIX 32768        // H*W per batch

typedef __attribute__((ext_vector_type(8))) short bf16x8;
typedef __attribute__((ext_vector_type(4))) float f32x4;

__device__ __forceinline__ ushort f2bf(float f) {
  union { float f; uint32_t u; } v; v.f = f;
  uint32_t r = v.u + 0x7fffu + ((v.u >> 16) & 1u);  // round-to-nearest-even
  return (ushort)(r >> 16);
}
__device__ __forceinline__ float bf2f(ushort h) {
  union { uint32_t u; float f; } v; v.u = ((uint32_t)h) << 16;
  return v.f;
}
__device__ __forceinline__ void gload_lds16(const void* g, void* lds) {
  __builtin_amdgcn_global_load_lds((__attribute__((address_space(1))) void*)g,
                                   (__attribute__((address_space(3))) void*)lds,
                                   16, 0, 0);
}

// ---------------------------------------------------------------------------
// Unified MFMA GEMM (three 1x1 convs). Coalesced+swizzled staging (R3, kept):
//   A/B LDS layout [row 128][oct 4][8ci], oct XOR-swizzled by ((row>>1)&3):
//   staging reads 16 rows x 64B contiguous per instr, frag ds_read_b128
//   conflict-free.
// ---------------------------------------------------------------------------
template <int BMODE, int OMODE>
__global__ __launch_bounds__(256) void mfma_gemm(
    const ushort* __restrict__ A, const ushort* __restrict__ B,
    const float* __restrict__ bn, void* __restrict__ OutV,
    int M, int K, int pitchB, int ciB, long strideB, int pitchO, long strideO) {
  const int lane = threadIdx.x & 63;
  const int wave = threadIdx.x >> 6;
  const int wm = (wave & 1) * 64;
  const int wn = (wave >> 1) * 64;
  const int m0 = blockIdx.y * 128;
  const int n0 = blockIdx.x * 128;
  const int z  = blockIdx.z;
  B += (size_t)z * strideB;

  const int h = n0 >> 8, w0 = n0 & 255;
  long prowB;
  if (BMODE == 0) prowB = n0;
  else            prowB = (long)(h + 1) * PADW + (w0 + 1);

  __shared__ __align__(16) ushort Asl[4 * 128 * 8];
  __shared__ __align__(16) ushort Bsl[4 * 128 * 8];

  f32x4 acc[4][4];
#pragma unroll
  for (int mt = 0; mt < 4; ++mt)
#pragma unroll
    for (int nt = 0; nt < 4; ++nt) acc[mt][nt] = (f32x4){0.f, 0.f, 0.f, 0.f};

  for (int k0 = 0; k0 < K; k0 += 32) {
#pragma unroll
    for (int i = 0; i < 2; ++i) {
      int c = (wave * 2 + i) * 64 + lane;       // chunk [0,512)
      int mm = c >> 2, g = (c & 3) ^ ((mm >> 1) & 3);
      gload_lds16(A + (size_t)(m0 + mm) * K + (k0 + g * 8), Asl + c * 8);
    }
    long rowb; int cib;
    if (BMODE == 2) {
      int tap = k0 >> 10;
      int dy = tap / 3 - 1, dx = tap % 3 - 1;
      rowb = prowB + dy * PADW + dx;
      cib  = k0 & 1023;
    } else {
      rowb = prowB;
      cib  = ciB + k0;
    }
#pragma unroll
    for (int i = 0; i < 2; ++i) {
      int c = (wave * 2 + i) * 64 + lane;
      int nn = c >> 2, g = (c & 3) ^ ((nn >> 1) & 3);
      gload_lds16(B + (size_t)(rowb + nn) * pitchB + cib + g * 8, Bsl + c * 8);
    }
    __syncthreads();
    bf16x8 af[4], bfr[4];
#pragma unroll
    for (int t = 0; t < 4; ++t) {
      int ks = lane >> 4;
      int ma = wm + t * 16 + (lane & 15);
      int nb = wn + t * 16 + (lane & 15);
      af[t]  = *(const bf16x8*)(Asl + (ma * 4 + (ks ^ ((ma >> 1) & 3))) * 8);
      bfr[t] = *(const bf16x8*)(Bsl + (nb * 4 + (ks ^ ((nb >> 1) & 3))) * 8);
    }
#pragma unroll
    for (int mt = 0; mt < 4; ++mt)
#pragma unroll
      for (int nt = 0; nt < 4; ++nt)
        acc[mt][nt] = __builtin_amdgcn_mfma_f32_16x16x32_bf16(af[mt], bfr[nt], acc[mt][nt], 0, 0, 0);
    __syncthreads();
  }

  const int q4 = lane >> 4, col = lane & 15;
  float scv[16], bov[16];
#pragma unroll
  for (int mt = 0; mt < 4; ++mt)
#pragma unroll
    for (int r = 0; r < 4; ++r) {
      int m = m0 + wm + mt * 16 + q4 * 4 + r;
      float s = bn[m] * rsqrtf(bn[3 * M + m] + EPS);
      scv[mt * 4 + r] = s;
      bov[mt * 4 + r] = bn[M + m] - bn[2 * M + m] * s;
    }
  if (OMODE == 2) {
    float* Outf = (float*)OutV + (size_t)z * strideO;
#pragma unroll
    for (int mt = 0; mt < 4; ++mt)
#pragma unroll
      for (int r = 0; r < 4; ++r) {
        int m = m0 + wm + mt * 16 + q4 * 4 + r;
        float* rowp = Outf + (size_t)m * NPIX + n0 + wn;
#pragma unroll
        for (int nt = 0; nt < 4; ++nt)
          rowp[nt * 16 + col] = fmaxf(acc[mt][nt][r] * scv[mt * 4 + r] + bov[mt * 4 + r], 0.f);
      }
  } else {
    ushort* Outh = (ushort*)OutV + (size_t)z * strideO;
    long prowO = (OMODE == 0) ? (long)n0 : ((long)(h + 1) * PADW + (w0 + 1));
#pragma unroll
    for (int nt = 0; nt < 4; ++nt) {
      long row = prowO + wn + nt * 16 + col;
      ushort* p = Outh + (size_t)row * pitchO + m0 + wm;
#pragma unroll
      for (int mt = 0; mt < 4; ++mt) {
        ushort4 pk;
        pk.x = f2bf(fmaxf(acc[mt][nt][0] * scv[mt * 4 + 0] + bov[mt * 4 + 0], 0.f));
        pk.y = f2bf(fmaxf(acc[mt][nt][1] * scv[mt * 4 + 1] + bov[mt * 4 + 1], 0.f));
        pk.z = f2bf(fmaxf(acc[mt][nt][2] * scv[mt * 4 + 2] + bov[mt * 4 + 2], 0.f));
        pk.w = f2bf(fmaxf(acc[mt][nt][3] * scv[mt * 4 + 3] + bov[mt * 4 + 3], 0.f));
        *(ushort4*)(p + mt * 16 + q4 * 4) = pk;
      }
    }
  }
}

// ---------------------------------------------------------------------------
// Conv3x3 halo-LDS implicit GEMM, round 7 (= R2 structure + budgeted pingpong):
//   * R2-proven skeleton: A-prologue at iter top (before staging, so stage
//     loads never poison A waits), __syncthreads at iter end. (R3's raw
//     barrier + rotated prologue spilled: unified VGPR+AGPR cap at 3
//     waves/SIMD is ~170; R3 needed ~180 -> +38MB scratch writes.)
//   * bfr ping-pong: tap t+1's 4 ds_read_b128 issued before tap t's MFMA
//     cluster -> per-tap lgkm latency hidden (+32 regs).
//   * Paid for by: af ring 3->2 (-16), hoff[12]->hoff0[3] (-9; nt-stride is
//     exactly +1024B since ((p+16)>>1)&3 == (p>>1)&3, folds into ds_read
//     immediate), offs long->int (-7). Net ~148-158 unified regs <= 170.
// ---------------------------------------------------------------------------
#define PXS  130          // pixels per halo row (128 + 2 halo)
#define ROWC (PXS * 4)    // 520 chunks per row
#define BUFC (3 * ROWC)   // 1560 chunks per buffer (24,960 B)
__global__ __launch_bounds__(256, 3) void conv3x3_mfma(
    const ushort* __restrict__ W2, const ushort* __restrict__ cat,
    const float* __restrict__ bn, float* __restrict__ out) {
  const int tid  = threadIdx.x;
  const int lane = tid & 63;
  const int wave = tid >> 6;
  const int wm = (wave & 1) * 64;
  const int wn = (wave >> 1) * 64;
  const int m0 = (blockIdx.x & 3) * 128;
  const int n0 = (blockIdx.x >> 2) * 128;
  const int z  = blockIdx.z;
  const int h = n0 >> 8, w0 = n0 & 255;
  const int prow0 = (h + 1) * PADW + (w0 + 1);
  const ushort* Bz = cat + (size_t)z * PADROWS * 1024;

  __shared__ __align__(16) ushort halo[2 * BUFC * 8];  // 49,920 B

  f32x4 acc[4][4];
#pragma unroll
  for (int mt = 0; mt < 4; ++mt)
#pragma unroll
    for (int nt = 0; nt < 4; ++nt) acc[mt][nt] = (f32x4){0.f, 0.f, 0.f, 0.f};

  // Per-thread staging source offsets (ushort units, ci-independent, 32-bit).
  // LDS slot chunk c = (r*130 + p)*4 + o_slot holds GLOBAL octet
  // o_g = o_slot ^ ((p>>1)&3)  (pre-swizzled source, linear LDS dest).
  int offs[7];
#pragma unroll
  for (int s = 0; s < 7; ++s) {
    int c = s * 256 + tid;
    if (c < BUFC) {
      int o_slot = c & 3;
      int q = c >> 2;
      int p = q % PXS;
      int r = q / PXS;
      int o_g = o_slot ^ ((p >> 1) & 3);
      offs[s] = ((prow0 + (r - 1) * PADW + (p - 1)) << 10) + o_g * 8;
    } else {
      offs[s] = -1;
    }
  }

  auto stage = [&](int buf, int ci0n) {
#pragma unroll
    for (int s = 0; s < 7; ++s)
      if (offs[s] >= 0)
        gload_lds16(Bz + (size_t)offs[s] + ci0n,
                    halo + ((size_t)buf * BUFC + s * 256 + wave * 64) * 8);
  };

  // Per-lane A base inside one (chunk,tap) 512x32 block:
  //   co = m0 + wm + mt*16 + (lane&15), octet = lane>>4.
  const ushort* Alane = W2 + (size_t)(m0 + wm + (lane & 15)) * 32 + (lane >> 4) * 8;

  // Swizzled halo byte offsets for dx=0,1,2 at nt=0; nt adds exactly nt*1024B
  // (swizzle term invariant under p += 16), folded into ds_read immediates.
  const int p0  = wn + (lane & 15);
  const int oct = lane >> 4;
  int hoff0[3];
#pragma unroll
  for (int dx = 0; dx < 3; ++dx) {
    int p = p0 + dx;
    hoff0[dx] = (p * 4 + (oct ^ ((p >> 1) & 3))) * 16;  // bytes
  }

  stage(0, 0);
  __syncthreads();

  for (int it = 0; it < 32; ++it) {
    const ushort* Ait = Alane + (size_t)it * (9 * 16384);

    // Prologue: A-frags for taps 0-1 (ring depth 2), BEFORE staging issue.
    bf16x8 af[2][4];
#pragma unroll
    for (int t = 0; t < 2; ++t)
#pragma unroll
      for (int mt = 0; mt < 4; ++mt)
        af[t][mt] = *(const bf16x8*)(Ait + (size_t)t * 16384 + mt * 512);

    __builtin_amdgcn_sched_barrier(0);
    if (it < 31) stage((it + 1) & 1, (it + 1) * 32);
    __builtin_amdgcn_sched_barrier(0);

    const char* hb0 = (const char*)(halo + (size_t)(it & 1) * BUFC * 8);
    bf16x8 bfr[2][4];
#pragma unroll
    for (int nt = 0; nt < 4; ++nt)
      bfr[0][nt] = *(const bf16x8*)(hb0 + nt * 1024 + hoff0[0]);

#pragma unroll
    for (int t = 0; t < 9; ++t) {
      if (t < 8) {  // prefetch next tap's B frags into the other bfr set
        const int r1 = (t + 1) / 3, dx1 = (t + 1) % 3;
#pragma unroll
        for (int nt = 0; nt < 4; ++nt)
          bfr[(t + 1) & 1][nt] =
              *(const bf16x8*)(hb0 + r1 * (ROWC * 16) + nt * 1024 + hoff0[dx1]);
      }
      __builtin_amdgcn_s_setprio(1);
#pragma unroll
      for (int nt = 0; nt < 4; ++nt)
#pragma unroll
        for (int mt = 0; mt < 4; ++mt)
          acc[mt][nt] = __builtin_amdgcn_mfma_f32_16x16x32_bf16(
              af[t & 1][mt], bfr[t & 1][nt], acc[mt][nt], 0, 0, 0);
      __builtin_amdgcn_s_setprio(0);
      if (t < 7) {  // ring refill: tap t+2 of this iter into the slot just read
#pragma unroll
        for (int mt = 0; mt < 4; ++mt)
          af[t & 1][mt] = *(const bf16x8*)(Ait + (size_t)(t + 2) * 16384 + mt * 512);
      }
    }
    __syncthreads();
  }

  // Epilogue: BN + ReLU, fp32 NCHW out.
  const int q4 = lane >> 4, col = lane & 15;
  float* Outf = out + (size_t)z * 512 * NPIX;
#pragma unroll
  for (int mt = 0; mt < 4; ++mt)
#pragma unroll
    for (int r = 0; r < 4; ++r) {
      int m = m0 + wm + mt * 16 + q4 * 4 + r;
      float s  = bn[m] * rsqrtf(bn[3 * 512 + m] + EPS);
      float bo = bn[512 + m] - bn[2 * 512 + m] * s;
      float* rowp = Outf + (size_t)m * NPIX + n0 + wn;
#pragma unroll
      for (int nt = 0; nt < 4; ++nt)
        rowp[nt * 16 + col] = fmaxf(acc[mt][nt][r] * s + bo, 0.f);
    }
}

// ---------------------------------------------------------------------------
// Tiny GEMM for the k/v path (fp32, negligible cost)
// ---------------------------------------------------------------------------
__global__ __launch_bounds__(64) void small_gemm_kernel(
    const float* __restrict__ Wm, const float* __restrict__ X,
    const float* __restrict__ bn, float* __restrict__ Y,
    int CO, int CI, int KC) {
  int co = blockIdx.x, b = blockIdx.y, kc = threadIdx.x;
  if (kc >= KC) return;
  const float* Xb = X + (size_t)b * CI * KC;
  float acc = 0.f;
  for (int c = 0; c < CI; ++c) acc += Wm[(size_t)co * CI + c] * Xb[(size_t)c * KC + kc];
  float s  = bn[co] * rsqrtf(bn[3 * CO + co] + EPS);
  float bs = bn[CO + co] - bn[2 * CO + co] * s;
  Y[((size_t)b * CO + co) * KC + kc] = fmaxf(acc * s + bs, 0.f);
}

// ---------------------------------------------------------------------------
// Attention: qT/ctxT in [pixel][256ch] bf16; k/v fp32 staged in LDS.
// ---------------------------------------------------------------------------
__global__ __launch_bounds__(256) void attention_kernel(
    const ushort* __restrict__ qT, const float* __restrict__ Kp,
    const float* __restrict__ Vp, ushort* __restrict__ ctxT) {
  int b = blockIdx.y;
  int pix = blockIdx.x * 256 + threadIdx.x;
  __shared__ float ks[256][19], vs[256][19];
  for (int idx = threadIdx.x; idx < 256 * 19; idx += 256) {
    int c = idx / 19, kk = idx % 19;
    ks[c][kk] = Kp[((size_t)b * 256 + c) * 19 + kk];
    vs[c][kk] = Vp[((size_t)b * 256 + c) * 19 + kk];
  }
  __syncthreads();

  const ushort* qrow = qT + ((size_t)b * NPIX + pix) * 256;
  float sim[19];
#pragma unroll
  for (int kk = 0; kk < 19; ++kk) sim[kk] = 0.f;
  for (int c0 = 0; c0 < 256; c0 += 8) {
    uint4 raw = *(const uint4*)(qrow + c0);
    float qf[8] = {bf2f((ushort)(raw.x & 0xffff)), bf2f((ushort)(raw.x >> 16)),
                   bf2f((ushort)(raw.y & 0xffff)), bf2f((ushort)(raw.y >> 16)),
                   bf2f((ushort)(raw.z & 0xffff)), bf2f((ushort)(raw.z >> 16)),
                   bf2f((ushort)(raw.w & 0xffff)), bf2f((ushort)(raw.w >> 16))};
#pragma unroll
    for (int j = 0; j < 8; ++j)
#pragma unroll
      for (int kk = 0; kk < 19; ++kk) sim[kk] += qf[j] * ks[c0 + j][kk];
  }
  const float scale = 0.0625f;
  float mx = -1e30f;
#pragma unroll
  for (int kk = 0; kk < 19; ++kk) { sim[kk] *= scale; mx = fmaxf(mx, sim[kk]); }
  float denom = 0.f;
#pragma unroll
  for (int kk = 0; kk < 19; ++kk) { sim[kk] = __expf(sim[kk] - mx); denom += sim[kk]; }
  float inv = 1.f / denom;
#pragma unroll
  for (int kk = 0; kk < 19; ++kk) sim[kk] *= inv;

  ushort* crow = ctxT + ((size_t)b * NPIX + pix) * 256;
  for (int c0 = 0; c0 < 256; c0 += 8) {
    uint32_t o[4];
#pragma unroll
    for (int j = 0; j < 4; ++j) {
      float v0 = 0.f, v1 = 0.f;
#pragma unroll
      for (int kk = 0; kk < 19; ++kk) {
        v0 += sim[kk] * vs[c0 + j * 2][kk];
        v1 += sim[kk] * vs[c0 + j * 2 + 1][kk];
      }
      o[j] = (uint32_t)f2bf(v0) | ((uint32_t)f2bf(v1) << 16);
    }
    *(uint4*)(crow + c0) = make_uint4(o[0], o[1], o[2], o[3]);
  }
}

// ---------------------------------------------------------------------------
// Transpose x (fp32 [b][512][HW]) into cat_pad (bf16 [b][p][1024], ch 512..1023)
// ---------------------------------------------------------------------------
__global__ __launch_bounds__(256) void transpose_x_kernel(
    const float* __restrict__ x, ushort* __restrict__ cat) {
  int b = blockIdx.z, ci0 = blockIdx.y * 64, n0 = blockIdx.x * 64;
  __shared__ float t[64][65];
  const float* xb = x + ((size_t)b * 512 + ci0) * NPIX + n0;
  for (int i = 0; i < 16; ++i) {
    int idx = i * 256 + threadIdx.x;
    int c = idx >> 6, w = idx & 63;
    t[c][w] = xb[(size_t)c * NPIX + w];
  }
  __syncthreads();
  int h = n0 >> 8, w0 = n0 & 255;
  size_t pbase = ((size_t)b * PADROWS + (size_t)(h + 1) * PADW + (w0 + 1)) * 1024 + 512 + ci0;
  for (int i = 0; i < 16; ++i) {
    int idx = i * 256 + threadIdx.x;
    int n = idx >> 6, c = idx & 63;
    cat[pbase + (size_t)n * 1024 + c] = f2bf(t[c][n]);
  }
}

// ---------------------------------------------------------------------------
// Weight conversions
// ---------------------------------------------------------------------------
__global__ void convert_w_kernel(const float* __restrict__ in, ushort* __restrict__ out, int n) {
  int i = blockIdx.x * 256 + threadIdx.x;
  if (i < n) out[i] = f2bf(in[i]);
}
// Repack wbot (co,ci,ky,kx) fp32 -> W2 bf16 [ci_chunk 32][tap 9][co 512][32 ci]
__global__ void repack_conv_w_kernel(const float* __restrict__ wbot, ushort* __restrict__ Wrb) {
  int idx = blockIdx.x * 256 + threadIdx.x;
  if (idx >= 512 * 9216) return;
  int ci_in = idx & 31;
  int r  = idx >> 5;
  int co = r & 511;
  int tt = r >> 9;
  int t = tt % 9, chunk = tt / 9;
  Wrb[idx] = f2bf(wbot[((size_t)co * 1024 + chunk * 32 + ci_in) * 9 + t]);
}

// ---------------------------------------------------------------------------
extern "C" void kernel_launch(void* const* d_in, const int* in_sizes, int n_in,
                              void* d_out, int out_size, void* d_ws, size_t ws_size,
                              hipStream_t stream) {
  const float* x     = (const float*)d_in[0];
  const float* proxy = (const float*)d_in[1];
  const float* wq1   = (const float*)d_in[2];
  const float* bnq1  = (const float*)d_in[3];
  const float* wq2   = (const float*)d_in[4];
  const float* bnq2  = (const float*)d_in[5];
  const float* wk1   = (const float*)d_in[6];
  const float* bnk1  = (const float*)d_in[7];
  const float* wk2   = (const float*)d_in[8];
  const float* bnk2  = (const float*)d_in[9];
  const float* wv    = (const float*)d_in[10];
  const float* bnv   = (const float*)d_in[11];
  const float* wout  = (const float*)d_in[12];
  const float* bnout = (const float*)d_in[13];
  const float* wbot  = (const float*)d_in[14];
  const float* bnbot = (const float*)d_in[15];
  float* out = (float*)d_out;

  const int B = 2, C = 512, CK = 256, KC = 19;
  char* ws = (char*)d_ws;
  const size_t catBytes = (size_t)B * PADROWS * 1024 * 2;  // 137,379,840
  ushort* cat  = (ushort*)ws;
  ushort* bufA = (ushort*)(ws + 137379840);                // q1T, later ctxT (32 MiB)
  ushort* bufB = (ushort*)(ws + 137379840 + 33554432);     // qT (32 MiB)
  ushort* Wrb  = (ushort*)(ws + 204488704);                // 9 MiB
  ushort* wq1b = (ushort*)(ws + 213925888);
  ushort* wq2b = (ushort*)(ws + 214188032);
  ushort* woutb= (ushort*)(ws + 214319104);
  float*  k1   = (float*)(ws + 214581248);
  float*  k2   = k1 + (size_t)B * CK * KC;
  float*  vv   = k2 + (size_t)B * CK * KC;

  hipMemsetAsync(cat, 0, catBytes, stream);

  convert_w_kernel<<<(CK * C + 255) / 256, 256, 0, stream>>>(wq1, wq1b, CK * C);
  convert_w_kernel<<<(CK * CK + 255) / 256, 256, 0, stream>>>(wq2, wq2b, CK * CK);
  convert_w_kernel<<<(C * CK + 255) / 256, 256, 0, stream>>>(wout, woutb, C * CK);
  repack_conv_w_kernel<<<(512 * 9216 + 255) / 256, 256, 0, stream>>>(wbot, Wrb);

  small_gemm_kernel<<<dim3(CK, B), 64, 0, stream>>>(wk1, proxy, bnk1, k1, CK, C, KC);
  small_gemm_kernel<<<dim3(CK, B), 64, 0, stream>>>(wk2, k1, bnk2, k2, CK, CK, KC);
  small_gemm_kernel<<<dim3(CK, B), 64, 0, stream>>>(wv, proxy, bnv, vv, CK, C, KC);

  transpose_x_kernel<<<dim3(NPIX / 64, 8, B), 256, 0, stream>>>(x, cat);

  const long padStride = (long)PADROWS * 1024;
  const long nckStride = (long)NPIX * 256;

  mfma_gemm<1, 0><<<dim3(NPIX / 128, 2, B), 256, 0, stream>>>(
      wq1b, cat, bnq1, bufA, 256, 512, 1024, 512, padStride, 256, nckStride);
  mfma_gemm<0, 0><<<dim3(NPIX / 128, 2, B), 256, 0, stream>>>(
      wq2b, bufA, bnq2, bufB, 256, 256, 256, 0, nckStride, 256, nckStride);

  attention_kernel<<<dim3(NPIX / 256, B), 256, 0, stream>>>(bufB, k2, vv, bufA);

  mfma_gemm<0, 1><<<dim3(NPIX / 128, 4, B), 256, 0, stream>>>(
      woutb, bufA, bnout, cat, 512, 256, 256, 0, nckStride, 1024, padStride);

  // conv3x3: halo-LDS implicit GEMM; grid.x = n_tile*4 + m_tile (XCD swizzle)
  conv3x3_mfma<<<dim3((NPIX / 128) * 4, 1, B), 256, 0, stream>>>(Wrb, cat, bnbot, out);
}

// Round 5
// 1104.650 us; speedup vs baseline: 1.2484x; 1.1554x over previous
//
#include <hip/hip_runtime.h>
#include <cstdint>

#define EPS 1e-5f
#define PADW 258          // W+2
#define PADROWS 33540     // (H+2)*(W+2) = 130*258
#define NPIX 32768        // H*W per batch

typedef __attribute__((ext_vector_type(8))) short bf16x8;
typedef __attribute__((ext_vector_type(4))) float f32x4;

__device__ __forceinline__ ushort f2bf(float f) {
  union { float f; uint32_t u; } v; v.f = f;
  uint32_t r = v.u + 0x7fffu + ((v.u >> 16) & 1u);  // round-to-nearest-even
  return (ushort)(r >> 16);
}
__device__ __forceinline__ float bf2f(ushort h) {
  union { uint32_t u; float f; } v; v.u = ((uint32_t)h) << 16;
  return v.f;
}
__device__ __forceinline__ void gload_lds16(const void* g, void* lds) {
  __builtin_amdgcn_global_load_lds((__attribute__((address_space(1))) void*)g,
                                   (__attribute__((address_space(3))) void*)lds,
                                   16, 0, 0);
}

// ---------------------------------------------------------------------------
// Unified MFMA GEMM (three 1x1 convs). Coalesced+swizzled staging (R3, kept):
//   A/B LDS layout [row 128][oct 4][8ci], oct XOR-swizzled by ((row>>1)&3):
//   staging reads 16 rows x 64B contiguous per instr, frag ds_read_b128
//   conflict-free.
// ---------------------------------------------------------------------------
template <int BMODE, int OMODE>
__global__ __launch_bounds__(256) void mfma_gemm(
    const ushort* __restrict__ A, const ushort* __restrict__ B,
    const float* __restrict__ bn, void* __restrict__ OutV,
    int M, int K, int pitchB, int ciB, long strideB, int pitchO, long strideO) {
  const int lane = threadIdx.x & 63;
  const int wave = threadIdx.x >> 6;
  const int wm = (wave & 1) * 64;
  const int wn = (wave >> 1) * 64;
  const int m0 = blockIdx.y * 128;
  const int n0 = blockIdx.x * 128;
  const int z  = blockIdx.z;
  B += (size_t)z * strideB;

  const int h = n0 >> 8, w0 = n0 & 255;
  long prowB;
  if (BMODE == 0) prowB = n0;
  else            prowB = (long)(h + 1) * PADW + (w0 + 1);

  __shared__ __align__(16) ushort Asl[4 * 128 * 8];
  __shared__ __align__(16) ushort Bsl[4 * 128 * 8];

  f32x4 acc[4][4];
#pragma unroll
  for (int mt = 0; mt < 4; ++mt)
#pragma unroll
    for (int nt = 0; nt < 4; ++nt) acc[mt][nt] = (f32x4){0.f, 0.f, 0.f, 0.f};

  for (int k0 = 0; k0 < K; k0 += 32) {
#pragma unroll
    for (int i = 0; i < 2; ++i) {
      int c = (wave * 2 + i) * 64 + lane;       // chunk [0,512)
      int mm = c >> 2, g = (c & 3) ^ ((mm >> 1) & 3);
      gload_lds16(A + (size_t)(m0 + mm) * K + (k0 + g * 8), Asl + c * 8);
    }
    long rowb; int cib;
    if (BMODE == 2) {
      int tap = k0 >> 10;
      int dy = tap / 3 - 1, dx = tap % 3 - 1;
      rowb = prowB + dy * PADW + dx;
      cib  = k0 & 1023;
    } else {
      rowb = prowB;
      cib  = ciB + k0;
    }
#pragma unroll
    for (int i = 0; i < 2; ++i) {
      int c = (wave * 2 + i) * 64 + lane;
      int nn = c >> 2, g = (c & 3) ^ ((nn >> 1) & 3);
      gload_lds16(B + (size_t)(rowb + nn) * pitchB + cib + g * 8, Bsl + c * 8);
    }
    __syncthreads();
    bf16x8 af[4], bfr[4];
#pragma unroll
    for (int t = 0; t < 4; ++t) {
      int ks = lane >> 4;
      int ma = wm + t * 16 + (lane & 15);
      int nb = wn + t * 16 + (lane & 15);
      af[t]  = *(const bf16x8*)(Asl + (ma * 4 + (ks ^ ((ma >> 1) & 3))) * 8);
      bfr[t] = *(const bf16x8*)(Bsl + (nb * 4 + (ks ^ ((nb >> 1) & 3))) * 8);
    }
#pragma unroll
    for (int mt = 0; mt < 4; ++mt)
#pragma unroll
      for (int nt = 0; nt < 4; ++nt)
        acc[mt][nt] = __builtin_amdgcn_mfma_f32_16x16x32_bf16(af[mt], bfr[nt], acc[mt][nt], 0, 0, 0);
    __syncthreads();
  }

  const int q4 = lane >> 4, col = lane & 15;
  float scv[16], bov[16];
#pragma unroll
  for (int mt = 0; mt < 4; ++mt)
#pragma unroll
    for (int r = 0; r < 4; ++r) {
      int m = m0 + wm + mt * 16 + q4 * 4 + r;
      float s = bn[m] * rsqrtf(bn[3 * M + m] + EPS);
      scv[mt * 4 + r] = s;
      bov[mt * 4 + r] = bn[M + m] - bn[2 * M + m] * s;
    }
  if (OMODE == 2) {
    float* Outf = (float*)OutV + (size_t)z * strideO;
#pragma unroll
    for (int mt = 0; mt < 4; ++mt)
#pragma unroll
      for (int r = 0; r < 4; ++r) {
        int m = m0 + wm + mt * 16 + q4 * 4 + r;
        float* rowp = Outf + (size_t)m * NPIX + n0 + wn;
#pragma unroll
        for (int nt = 0; nt < 4; ++nt)
          rowp[nt * 16 + col] = fmaxf(acc[mt][nt][r] * scv[mt * 4 + r] + bov[mt * 4 + r], 0.f);
      }
  } else {
    ushort* Outh = (ushort*)OutV + (size_t)z * strideO;
    long prowO = (OMODE == 0) ? (long)n0 : ((long)(h + 1) * PADW + (w0 + 1));
#pragma unroll
    for (int nt = 0; nt < 4; ++nt) {
      long row = prowO + wn + nt * 16 + col;
      ushort* p = Outh + (size_t)row * pitchO + m0 + wm;
#pragma unroll
      for (int mt = 0; mt < 4; ++mt) {
        ushort4 pk;
        pk.x = f2bf(fmaxf(acc[mt][nt][0] * scv[mt * 4 + 0] + bov[mt * 4 + 0], 0.f));
        pk.y = f2bf(fmaxf(acc[mt][nt][1] * scv[mt * 4 + 1] + bov[mt * 4 + 1], 0.f));
        pk.z = f2bf(fmaxf(acc[mt][nt][2] * scv[mt * 4 + 2] + bov[mt * 4 + 2], 0.f));
        pk.w = f2bf(fmaxf(acc[mt][nt][3] * scv[mt * 4 + 3] + bov[mt * 4 + 3], 0.f));
        *(ushort4*)(p + mt * 16 + q4 * 4) = pk;
      }
    }
  }
}

// ---------------------------------------------------------------------------
// Conv3x3 halo-LDS implicit GEMM, round 8: m201-style 8-phase schedule.
// Per tap-phase: {4 ds_read bfr | 1 staging gload_lds (taps 0-6) -> s_barrier
// -> lgkmcnt(0) -> setprio(1) 16 MFMA setprio(0) -> af refills} with a single
// counted s_waitcnt vmcnt(8) per iter at tap 8 (exactly the 8 next-iter
// A-prologue loads issued after the last stage instr remain in flight).
// No vmcnt(0) in the main loop (T3+T4); per-phase barrier pairs create the
// wave role-split that makes setprio pay (T5 gate).
// ---------------------------------------------------------------------------
#define PXS  130          // pixels per halo row (128 + 2 halo)
#define ROWC (PXS * 4)    // 520 chunks per row
#define BUFC (3 * ROWC)   // 1560 chunks per buffer (24,960 B)
__global__ __launch_bounds__(256, 3) void conv3x3_mfma(
    const ushort* __restrict__ W2, const ushort* __restrict__ cat,
    const float* __restrict__ bn, float* __restrict__ out) {
  const int tid  = threadIdx.x;
  const int lane = tid & 63;
  const int wave = tid >> 6;
  const int wm = (wave & 1) * 64;
  const int wn = (wave >> 1) * 64;
  const int m0 = (blockIdx.x & 3) * 128;
  const int n0 = (blockIdx.x >> 2) * 128;
  const int z  = blockIdx.z;
  const int h = n0 >> 8, w0 = n0 & 255;
  const int prow0 = (h + 1) * PADW + (w0 + 1);
  const ushort* Bz = cat + (size_t)z * PADROWS * 1024;

  __shared__ __align__(16) ushort halo[2 * BUFC * 8];  // 49,920 B

  f32x4 acc[4][4];
#pragma unroll
  for (int mt = 0; mt < 4; ++mt)
#pragma unroll
    for (int nt = 0; nt < 4; ++nt) acc[mt][nt] = (f32x4){0.f, 0.f, 0.f, 0.f};

  // Per-thread staging source offsets (ushort units, ci-independent, 32-bit).
  // LDS slot chunk c = (r*130 + p)*4 + o_slot holds GLOBAL octet
  // o_g = o_slot ^ ((p>>1)&3)  (pre-swizzled source, linear LDS dest).
  int offs[7];
#pragma unroll
  for (int s = 0; s < 7; ++s) {
    int c = s * 256 + tid;
    if (c < BUFC) {
      int o_slot = c & 3;
      int q = c >> 2;
      int p = q % PXS;
      int r = q / PXS;
      int o_g = o_slot ^ ((p >> 1) & 3);
      offs[s] = ((prow0 + (r - 1) * PADW + (p - 1)) << 10) + o_g * 8;
    } else {
      offs[s] = -1;
    }
  }

  // One staging chunk (per-thread) for phase s into buffer buf at ci offset.
  auto stage1 = [&](int s, int buf, int ci0n) {
    if (offs[s] >= 0)
      gload_lds16(Bz + (size_t)offs[s] + ci0n,
                  halo + ((size_t)buf * BUFC + s * 256 + wave * 64) * 8);
  };

  // Per-lane A base inside one (chunk,tap) 512x32 block:
  //   co = m0 + wm + mt*16 + (lane&15), octet = lane>>4.
  const ushort* Alane = W2 + (size_t)(m0 + wm + (lane & 15)) * 32 + (lane >> 4) * 8;

  // Swizzled halo byte offsets for dx=0,1,2 at nt=0; nt adds exactly nt*1024B
  // (swizzle term invariant under p += 16), folded into ds_read immediates.
  const int p0  = wn + (lane & 15);
  const int oct = lane >> 4;
  int hoff0[3];
#pragma unroll
  for (int dx = 0; dx < 3; ++dx) {
    int p = p0 + dx;
    hoff0[dx] = (p * 4 + (oct ^ ((p >> 1) & 3))) * 16;  // bytes
  }

  // Prologue: stage all of buf0 (7 instrs), then iter-0 taps 0-1 A-frags
  // (8 loads). vmcnt(8) -> staging retired, A-prologue stays in flight.
#pragma unroll
  for (int s = 0; s < 7; ++s) stage1(s, 0, 0);
  bf16x8 af[2][4];
#pragma unroll
  for (int t = 0; t < 2; ++t)
#pragma unroll
    for (int mt = 0; mt < 4; ++mt)
      af[t][mt] = *(const bf16x8*)(Alane + (size_t)t * 16384 + mt * 512);
  asm volatile("s_waitcnt vmcnt(8)" ::: "memory");
  __builtin_amdgcn_sched_barrier(0);
  __builtin_amdgcn_s_barrier();

  for (int it = 0; it < 32; ++it) {
    const ushort* Ait = Alane + (size_t)it * (9 * 16384);
    const ushort* An  = Ait + (size_t)(9 * 16384);
    const char* hb0 = (const char*)(halo + (size_t)(it & 1) * BUFC * 8);
    const int nbuf = (it + 1) & 1;
    const int nci  = (it + 1) * 32;
    const bool more = (it < 31);

#pragma unroll
    for (int t = 0; t < 9; ++t) {
      const int r = t / 3, dx = t % 3;
      // Phase load: this tap's 4 B-frags from LDS.
      bf16x8 bfr[4];
#pragma unroll
      for (int nt = 0; nt < 4; ++nt)
        bfr[nt] = *(const bf16x8*)(hb0 + r * (ROWC * 16) + nt * 1024 + hoff0[dx]);
      // One staging chunk for the next iter's buffer (taps 0-6).
      if (t < 7 && more) stage1(t, nbuf, nci);
      __builtin_amdgcn_s_barrier();
      asm volatile("s_waitcnt lgkmcnt(0)" ::: "memory");
      __builtin_amdgcn_sched_barrier(0);
      __builtin_amdgcn_s_setprio(1);
#pragma unroll
      for (int nt = 0; nt < 4; ++nt)
#pragma unroll
        for (int mt = 0; mt < 4; ++mt)
          acc[mt][nt] = __builtin_amdgcn_mfma_f32_16x16x32_bf16(
              af[t & 1][mt], bfr[nt], acc[mt][nt], 0, 0, 0);
      __builtin_amdgcn_s_setprio(0);
      // A refills: taps 0-6 refill tap t+2 (slot just consumed); tap 8 loads
      // the next iter's taps 0-1 prologue (both slots free after tap 8).
      if (t < 7) {
#pragma unroll
        for (int mt = 0; mt < 4; ++mt)
          af[t & 1][mt] = *(const bf16x8*)(Ait + (size_t)(t + 2) * 16384 + mt * 512);
      } else if (t == 8 && more) {
#pragma unroll
        for (int mt = 0; mt < 4; ++mt)
          af[0][mt] = *(const bf16x8*)(An + mt * 512);
#pragma unroll
        for (int mt = 0; mt < 4; ++mt)
          af[1][mt] = *(const bf16x8*)(An + 16384 + mt * 512);
      }
      if (t == 8) {
        // Counted drain: next-iter staging (issued taps 0-6) retired; only
        // the 8 A-prologue loads remain in flight across the barrier.
        asm volatile("s_waitcnt vmcnt(8)" ::: "memory");
        __builtin_amdgcn_sched_barrier(0);
      }
      __builtin_amdgcn_s_barrier();
    }
  }

  // Epilogue: BN + ReLU, fp32 NCHW out.
  const int q4 = lane >> 4, col = lane & 15;
  float* Outf = out + (size_t)z * 512 * NPIX;
#pragma unroll
  for (int mt = 0; mt < 4; ++mt)
#pragma unroll
    for (int r = 0; r < 4; ++r) {
      int m = m0 + wm + mt * 16 + q4 * 4 + r;
      float s  = bn[m] * rsqrtf(bn[3 * 512 + m] + EPS);
      float bo = bn[512 + m] - bn[2 * 512 + m] * s;
      float* rowp = Outf + (size_t)m * NPIX + n0 + wn;
#pragma unroll
      for (int nt = 0; nt < 4; ++nt)
        rowp[nt * 16 + col] = fmaxf(acc[mt][nt][r] * s + bo, 0.f);
    }
}

// ---------------------------------------------------------------------------
// Small GEMM for the k/v path: 4-way K-split + LDS reduce (was a 512-long
// serial load chain on 19 lanes of one wave).
// ---------------------------------------------------------------------------
__global__ __launch_bounds__(256) void small_gemm_kernel(
    const float* __restrict__ Wm, const float* __restrict__ X,
    const float* __restrict__ bn, float* __restrict__ Y,
    int CO, int CI, int KC) {
  int co = blockIdx.x, b = blockIdx.y;
  int q = threadIdx.x >> 6, kc = threadIdx.x & 63;
  __shared__ float part[3][24];
  const float* Xb = X + (size_t)b * CI * KC;
  const float* Wr = Wm + (size_t)co * CI;
  float acc = 0.f;
  int cq = CI >> 2;
  if (kc < KC) {
    for (int c = q * cq; c < (q + 1) * cq; ++c)
      acc += Wr[c] * Xb[(size_t)c * KC + kc];
  }
  if (q > 0 && kc < KC) part[q - 1][kc] = acc;
  __syncthreads();
  if (q == 0 && kc < KC) {
    acc += part[0][kc] + part[1][kc] + part[2][kc];
    float s  = bn[co] * rsqrtf(bn[3 * CO + co] + EPS);
    float bs = bn[CO + co] - bn[2 * CO + co] * s;
    Y[((size_t)b * CO + co) * KC + kc] = fmaxf(acc * s + bs, 0.f);
  }
}

// ---------------------------------------------------------------------------
// Attention: qT/ctxT in [pixel][256ch] bf16; k/v fp32 staged in LDS.
// ---------------------------------------------------------------------------
__global__ __launch_bounds__(256) void attention_kernel(
    const ushort* __restrict__ qT, const float* __restrict__ Kp,
    const float* __restrict__ Vp, ushort* __restrict__ ctxT) {
  int b = blockIdx.y;
  int pix = blockIdx.x * 256 + threadIdx.x;
  __shared__ float ks[256][19], vs[256][19];
  for (int idx = threadIdx.x; idx < 256 * 19; idx += 256) {
    int c = idx / 19, kk = idx % 19;
    ks[c][kk] = Kp[((size_t)b * 256 + c) * 19 + kk];
    vs[c][kk] = Vp[((size_t)b * 256 + c) * 19 + kk];
  }
  __syncthreads();

  const ushort* qrow = qT + ((size_t)b * NPIX + pix) * 256;
  float sim[19];
#pragma unroll
  for (int kk = 0; kk < 19; ++kk) sim[kk] = 0.f;
  for (int c0 = 0; c0 < 256; c0 += 8) {
    uint4 raw = *(const uint4*)(qrow + c0);
    float qf[8] = {bf2f((ushort)(raw.x & 0xffff)), bf2f((ushort)(raw.x >> 16)),
                   bf2f((ushort)(raw.y & 0xffff)), bf2f((ushort)(raw.y >> 16)),
                   bf2f((ushort)(raw.z & 0xffff)), bf2f((ushort)(raw.z >> 16)),
                   bf2f((ushort)(raw.w & 0xffff)), bf2f((ushort)(raw.w >> 16))};
#pragma unroll
    for (int j = 0; j < 8; ++j)
#pragma unroll
      for (int kk = 0; kk < 19; ++kk) sim[kk] += qf[j] * ks[c0 + j][kk];
  }
  const float scale = 0.0625f;
  float mx = -1e30f;
#pragma unroll
  for (int kk = 0; kk < 19; ++kk) { sim[kk] *= scale; mx = fmaxf(mx, sim[kk]); }
  float denom = 0.f;
#pragma unroll
  for (int kk = 0; kk < 19; ++kk) { sim[kk] = __expf(sim[kk] - mx); denom += sim[kk]; }
  float inv = 1.f / denom;
#pragma unroll
  for (int kk = 0; kk < 19; ++kk) sim[kk] *= inv;

  ushort* crow = ctxT + ((size_t)b * NPIX + pix) * 256;
  for (int c0 = 0; c0 < 256; c0 += 8) {
    uint32_t o[4];
#pragma unroll
    for (int j = 0; j < 4; ++j) {
      float v0 = 0.f, v1 = 0.f;
#pragma unroll
      for (int kk = 0; kk < 19; ++kk) {
        v0 += sim[kk] * vs[c0 + j * 2][kk];
        v1 += sim[kk] * vs[c0 + j * 2 + 1][kk];
      }
      o[j] = (uint32_t)f2bf(v0) | ((uint32_t)f2bf(v1) << 16);
    }
    *(uint4*)(crow + c0) = make_uint4(o[0], o[1], o[2], o[3]);
  }
}

// ---------------------------------------------------------------------------
// Transpose x (fp32 [b][512][HW]) into cat_pad (bf16 [b][p][1024], ch 512..1023)
// ---------------------------------------------------------------------------
__global__ __launch_bounds__(256) void transpose_x_kernel(
    const float* __restrict__ x, ushort* __restrict__ cat) {
  int b = blockIdx.z, ci0 = blockIdx.y * 64, n0 = blockIdx.x * 64;
  __shared__ float t[64][65];
  const float* xb = x + ((size_t)b * 512 + ci0) * NPIX + n0;
  for (int i = 0; i < 16; ++i) {
    int idx = i * 256 + threadIdx.x;
    int c = idx >> 6, w = idx & 63;
    t[c][w] = xb[(size_t)c * NPIX + w];
  }
  __syncthreads();
  int h = n0 >> 8, w0 = n0 & 255;
  size_t pbase = ((size_t)b * PADROWS + (size_t)(h + 1) * PADW + (w0 + 1)) * 1024 + 512 + ci0;
  for (int i = 0; i < 16; ++i) {
    int idx = i * 256 + threadIdx.x;
    int n = idx >> 6, c = idx & 63;
    cat[pbase + (size_t)n * 1024 + c] = f2bf(t[c][n]);
  }
}

// ---------------------------------------------------------------------------
// Zero only the pad border ring of cat (772 px/batch x 1024 ch = 1.58 MB vs
// the old 137 MB full memset). Interior px are fully overwritten by
// transpose_x (ch 512..1023) and the out-GEMM (ch 0..511).
// ---------------------------------------------------------------------------
__global__ __launch_bounds__(256) void zero_border_kernel(ushort* __restrict__ cat) {
  int b = blockIdx.y, i = blockIdx.x;
  int row, col;
  if (i < 258)      { row = 0;            col = i; }
  else if (i < 516) { row = 129;          col = i - 258; }
  else if (i < 644) { row = i - 516 + 1;  col = 0; }
  else              { row = i - 644 + 1;  col = 257; }
  size_t base = ((size_t)b * PADROWS + (size_t)row * PADW + col) * 1024 +
                (size_t)threadIdx.x * 4;
  *(ushort4*)(cat + base) = make_ushort4(0, 0, 0, 0);
}

// ---------------------------------------------------------------------------
// Weight conversions
// ---------------------------------------------------------------------------
__global__ void convert_w_kernel(const float* __restrict__ in, ushort* __restrict__ out, int n) {
  int i = blockIdx.x * 256 + threadIdx.x;
  if (i < n) out[i] = f2bf(in[i]);
}
// Repack wbot (co,ci,ky,kx) fp32 -> W2 bf16 [ci_chunk 32][tap 9][co 512][32 ci]
__global__ void repack_conv_w_kernel(const float* __restrict__ wbot, ushort* __restrict__ Wrb) {
  int idx = blockIdx.x * 256 + threadIdx.x;
  if (idx >= 512 * 9216) return;
  int ci_in = idx & 31;
  int r  = idx >> 5;
  int co = r & 511;
  int tt = r >> 9;
  int t = tt % 9, chunk = tt / 9;
  Wrb[idx] = f2bf(wbot[((size_t)co * 1024 + chunk * 32 + ci_in) * 9 + t]);
}

// ---------------------------------------------------------------------------
extern "C" void kernel_launch(void* const* d_in, const int* in_sizes, int n_in,
                              void* d_out, int out_size, void* d_ws, size_t ws_size,
                              hipStream_t stream) {
  const float* x     = (const float*)d_in[0];
  const float* proxy = (const float*)d_in[1];
  const float* wq1   = (const float*)d_in[2];
  const float* bnq1  = (const float*)d_in[3];
  const float* wq2   = (const float*)d_in[4];
  const float* bnq2  = (const float*)d_in[5];
  const float* wk1   = (const float*)d_in[6];
  const float* bnk1  = (const float*)d_in[7];
  const float* wk2   = (const float*)d_in[8];
  const float* bnk2  = (const float*)d_in[9];
  const float* wv    = (const float*)d_in[10];
  const float* bnv   = (const float*)d_in[11];
  const float* wout  = (const float*)d_in[12];
  const float* bnout = (const float*)d_in[13];
  const float* wbot  = (const float*)d_in[14];
  const float* bnbot = (const float*)d_in[15];
  float* out = (float*)d_out;

  const int B = 2, C = 512, CK = 256, KC = 19;
  char* ws = (char*)d_ws;
  ushort* cat  = (ushort*)ws;
  ushort* bufA = (ushort*)(ws + 137379840);                // q1T, later ctxT (32 MiB)
  ushort* bufB = (ushort*)(ws + 137379840 + 33554432);     // qT (32 MiB)
  ushort* Wrb  = (ushort*)(ws + 204488704);                // 9 MiB
  ushort* wq1b = (ushort*)(ws + 213925888);
  ushort* wq2b = (ushort*)(ws + 214188032);
  ushort* woutb= (ushort*)(ws + 214319104);
  float*  k1   = (float*)(ws + 214581248);
  float*  k2   = k1 + (size_t)B * CK * KC;
  float*  vv   = k2 + (size_t)B * CK * KC;

  zero_border_kernel<<<dim3(772, B), 256, 0, stream>>>(cat);

  convert_w_kernel<<<(CK * C + 255) / 256, 256, 0, stream>>>(wq1, wq1b, CK * C);
  convert_w_kernel<<<(CK * CK + 255) / 256, 256, 0, stream>>>(wq2, wq2b, CK * CK);
  convert_w_kernel<<<(C * CK + 255) / 256, 256, 0, stream>>>(wout, woutb, C * CK);
  repack_conv_w_kernel<<<(512 * 9216 + 255) / 256, 256, 0, stream>>>(wbot, Wrb);

  small_gemm_kernel<<<dim3(CK, B), 256, 0, stream>>>(wk1, proxy, bnk1, k1, CK, C, KC);
  small_gemm_kernel<<<dim3(CK, B), 256, 0, stream>>>(wk2, k1, bnk2, k2, CK, CK, KC);
  small_gemm_kernel<<<dim3(CK, B), 256, 0, stream>>>(wv, proxy, bnv, vv, CK, C, KC);

  transpose_x_kernel<<<dim3(NPIX / 64, 8, B), 256, 0, stream>>>(x, cat);

  const long padStride = (long)PADROWS * 1024;
  const long nckStride = (long)NPIX * 256;

  mfma_gemm<1, 0><<<dim3(NPIX / 128, 2, B), 256, 0, stream>>>(
      wq1b, cat, bnq1, bufA, 256, 512, 1024, 512, padStride, 256, nckStride);
  mfma_gemm<0, 0><<<dim3(NPIX / 128, 2, B), 256, 0, stream>>>(
      wq2b, bufA, bnq2, bufB, 256, 256, 256, 0, nckStride, 256, nckStride);

  attention_kernel<<<dim3(NPIX / 256, B), 256, 0, stream>>>(bufB, k2, vv, bufA);

  mfma_gemm<0, 1><<<dim3(NPIX / 128, 4, B), 256, 0, stream>>>(
      woutb, bufA, bnout, cat, 512, 256, 256, 0, nckStride, 1024, padStride);

  // conv3x3: halo-LDS implicit GEMM; grid.x = n_tile*4 + m_tile (XCD swizzle)
  conv3x3_mfma<<<dim3((NPIX / 128) * 4, 1, B), 256, 0, stream>>>(Wrb, cat, bnbot, out);
}

// Round 6
// 1044.862 us; speedup vs baseline: 1.3199x; 1.0572x over previous
//
#include <hip/hip_runtime.h>
#include <cstdint>

#define EPS 1e-5f
#define PADW 258          // W+2
#define PADROWS 33540     // (H+2)*(W+2) = 130*258
#define NPIX 32768        // H*W per batch

typedef __attribute__((ext_vector_type(8))) short bf16x8;
typedef __attribute__((ext_vector_type(4))) float f32x4;

__device__ __forceinline__ ushort f2bf(float f) {
  union { float f; uint32_t u; } v; v.f = f;
  uint32_t r = v.u + 0x7fffu + ((v.u >> 16) & 1u);  // round-to-nearest-even
  return (ushort)(r >> 16);
}
__device__ __forceinline__ float bf2f(ushort h) {
  union { uint32_t u; float f; } v; v.u = ((uint32_t)h) << 16;
  return v.f;
}
__device__ __forceinline__ void gload_lds16(const void* g, void* lds) {
  __builtin_amdgcn_global_load_lds((__attribute__((address_space(1))) void*)g,
                                   (__attribute__((address_space(3))) void*)lds,
                                   16, 0, 0);
}

// ---------------------------------------------------------------------------
// Unified MFMA GEMM (three 1x1 convs). Coalesced+swizzled staging:
//   A/B LDS layout [row 128][oct 4][8ci], oct XOR-swizzled by ((row>>1)&3).
// ---------------------------------------------------------------------------
template <int BMODE, int OMODE>
__global__ __launch_bounds__(256) void mfma_gemm(
    const ushort* __restrict__ A, const ushort* __restrict__ B,
    const float* __restrict__ bn, void* __restrict__ OutV,
    int M, int K, int pitchB, int ciB, long strideB, int pitchO, long strideO) {
  const int lane = threadIdx.x & 63;
  const int wave = threadIdx.x >> 6;
  const int wm = (wave & 1) * 64;
  const int wn = (wave >> 1) * 64;
  const int m0 = blockIdx.y * 128;
  const int n0 = blockIdx.x * 128;
  const int z  = blockIdx.z;
  B += (size_t)z * strideB;

  const int h = n0 >> 8, w0 = n0 & 255;
  long prowB;
  if (BMODE == 0) prowB = n0;
  else            prowB = (long)(h + 1) * PADW + (w0 + 1);

  __shared__ __align__(16) ushort Asl[4 * 128 * 8];
  __shared__ __align__(16) ushort Bsl[4 * 128 * 8];

  f32x4 acc[4][4];
#pragma unroll
  for (int mt = 0; mt < 4; ++mt)
#pragma unroll
    for (int nt = 0; nt < 4; ++nt) acc[mt][nt] = (f32x4){0.f, 0.f, 0.f, 0.f};

  for (int k0 = 0; k0 < K; k0 += 32) {
#pragma unroll
    for (int i = 0; i < 2; ++i) {
      int c = (wave * 2 + i) * 64 + lane;       // chunk [0,512)
      int mm = c >> 2, g = (c & 3) ^ ((mm >> 1) & 3);
      gload_lds16(A + (size_t)(m0 + mm) * K + (k0 + g * 8), Asl + c * 8);
    }
    long rowb; int cib;
    if (BMODE == 2) {
      int tap = k0 >> 10;
      int dy = tap / 3 - 1, dx = tap % 3 - 1;
      rowb = prowB + dy * PADW + dx;
      cib  = k0 & 1023;
    } else {
      rowb = prowB;
      cib  = ciB + k0;
    }
#pragma unroll
    for (int i = 0; i < 2; ++i) {
      int c = (wave * 2 + i) * 64 + lane;
      int nn = c >> 2, g = (c & 3) ^ ((nn >> 1) & 3);
      gload_lds16(B + (size_t)(rowb + nn) * pitchB + cib + g * 8, Bsl + c * 8);
    }
    __syncthreads();
    bf16x8 af[4], bfr[4];
#pragma unroll
    for (int t = 0; t < 4; ++t) {
      int ks = lane >> 4;
      int ma = wm + t * 16 + (lane & 15);
      int nb = wn + t * 16 + (lane & 15);
      af[t]  = *(const bf16x8*)(Asl + (ma * 4 + (ks ^ ((ma >> 1) & 3))) * 8);
      bfr[t] = *(const bf16x8*)(Bsl + (nb * 4 + (ks ^ ((nb >> 1) & 3))) * 8);
    }
#pragma unroll
    for (int mt = 0; mt < 4; ++mt)
#pragma unroll
      for (int nt = 0; nt < 4; ++nt)
        acc[mt][nt] = __builtin_amdgcn_mfma_f32_16x16x32_bf16(af[mt], bfr[nt], acc[mt][nt], 0, 0, 0);
    __syncthreads();
  }

  const int q4 = lane >> 4, col = lane & 15;
  float scv[16], bov[16];
#pragma unroll
  for (int mt = 0; mt < 4; ++mt)
#pragma unroll
    for (int r = 0; r < 4; ++r) {
      int m = m0 + wm + mt * 16 + q4 * 4 + r;
      float s = bn[m] * rsqrtf(bn[3 * M + m] + EPS);
      scv[mt * 4 + r] = s;
      bov[mt * 4 + r] = bn[M + m] - bn[2 * M + m] * s;
    }
  if (OMODE == 2) {
    float* Outf = (float*)OutV + (size_t)z * strideO;
#pragma unroll
    for (int mt = 0; mt < 4; ++mt)
#pragma unroll
      for (int r = 0; r < 4; ++r) {
        int m = m0 + wm + mt * 16 + q4 * 4 + r;
        float* rowp = Outf + (size_t)m * NPIX + n0 + wn;
#pragma unroll
        for (int nt = 0; nt < 4; ++nt)
          rowp[nt * 16 + col] = fmaxf(acc[mt][nt][r] * scv[mt * 4 + r] + bov[mt * 4 + r], 0.f);
      }
  } else {
    ushort* Outh = (ushort*)OutV + (size_t)z * strideO;
    long prowO = (OMODE == 0) ? (long)n0 : ((long)(h + 1) * PADW + (w0 + 1));
#pragma unroll
    for (int nt = 0; nt < 4; ++nt) {
      long row = prowO + wn + nt * 16 + col;
      ushort* p = Outh + (size_t)row * pitchO + m0 + wm;
#pragma unroll
      for (int mt = 0; mt < 4; ++mt) {
        ushort4 pk;
        pk.x = f2bf(fmaxf(acc[mt][nt][0] * scv[mt * 4 + 0] + bov[mt * 4 + 0], 0.f));
        pk.y = f2bf(fmaxf(acc[mt][nt][1] * scv[mt * 4 + 1] + bov[mt * 4 + 1], 0.f));
        pk.z = f2bf(fmaxf(acc[mt][nt][2] * scv[mt * 4 + 2] + bov[mt * 4 + 2], 0.f));
        pk.w = f2bf(fmaxf(acc[mt][nt][3] * scv[mt * 4 + 3] + bov[mt * 4 + 3], 0.f));
        *(ushort4*)(p + mt * 16 + q4 * 4) = pk;
      }
    }
  }
}

// ---------------------------------------------------------------------------
// Conv3x3, round 9: 256co x 256px tile, 8 waves (4m x 2n), m201 quadrant.
//   The 128²/4-wave/2-barrier structure was pinned at 41% MfmaUtil across
//   three schedule variants — the documented m97-structure ceiling. This is
//   the documented escape: 2 waves/SIMD + per-tap phase barriers + counted
//   vmcnt + setprio, with 4.6x less A-traffic per output (L2 relief).
//   n-tile = one full image row (W=256): halo = padded rows h..h+2, all 258
//   cols. LDS: 2 x 3584 slots x 16B = 114,688 B -> 1 block/CU.
//   Per tap-phase: {8 ds_read bfr | 1 stage gload_lds (taps 0-6) -> barrier
//   -> lgkmcnt(0) -> setprio(1) 32 MFMA setprio(0) -> af refill}; single
//   s_waitcnt vmcnt(8) per iter at tap 8.
// ---------------------------------------------------------------------------
#define PXS2  258          // pixels per halo row (full padded width)
#define ROWC2 (PXS2 * 4)   // 1032 chunks per row
#define BUFC2 (3 * ROWC2)  // 3096 chunks per buffer
#define SLOTS2 3584        // 7 * 512 (padded staging slots per buffer)
__global__ __launch_bounds__(512, 2) void conv3x3_mfma(
    const ushort* __restrict__ W2, const ushort* __restrict__ cat,
    const float* __restrict__ bn, float* __restrict__ out) {
  const int tid  = threadIdx.x;
  const int lane = tid & 63;
  const int wave = tid >> 6;
  const int wm  = (wave & 3) * 64;    // co offset within 256-co tile
  const int wnp = (wave >> 2) * 128;  // px offset within 256-px row
  const int m0 = (blockIdx.x & 1) * 256;
  const int h  = blockIdx.x >> 1;     // image row 0..127
  const int z  = blockIdx.z;
  const ushort* Bz = cat + (size_t)z * PADROWS * 1024;

  __shared__ __align__(16) ushort halo[2 * SLOTS2 * 8];  // 114,688 B

  f32x4 acc[4][8];
#pragma unroll
  for (int mt = 0; mt < 4; ++mt)
#pragma unroll
    for (int nt = 0; nt < 8; ++nt) acc[mt][nt] = (f32x4){0.f, 0.f, 0.f, 0.f};

  // Staging source offsets (ushort units, ci-independent, 32-bit).
  // Slot chunk c = (r*258 + p)*4 + o_slot holds GLOBAL octet
  // o_g = o_slot ^ ((p>>1)&3); source pixel = padded (h+r, p).
  int offs[7];
#pragma unroll
  for (int s = 0; s < 7; ++s) {
    int c = s * 512 + tid;
    if (c > BUFC2 - 1) c = BUFC2 - 1;  // pad slots re-load last chunk (benign)
    int o_slot = c & 3;
    int q = c >> 2;
    int p = q % PXS2;
    int r = q / PXS2;
    int o_g = o_slot ^ ((p >> 1) & 3);
    offs[s] = (((h + r) * PADW + p) << 10) + o_g * 8;
  }

  auto stage1 = [&](int s, int buf, int ci0n) {
    gload_lds16(Bz + (size_t)offs[s] + ci0n,
                halo + ((size_t)buf * SLOTS2 + s * 512 + wave * 64) * 8);
  };

  // Per-lane A base: co = m0 + wm + mt*16 + (lane&15), octet = lane>>4.
  // W2 layout [chunk 32][tap 9][co 512][32 ci].
  const ushort* Alane = W2 + (size_t)(m0 + wm + (lane & 15)) * 32 + (lane >> 4) * 8;

  // Swizzled halo byte offsets for dx=0..2 at nt=0; nt adds exactly nt*1024B.
  const int p0  = wnp + (lane & 15);
  const int oct = lane >> 4;
  int hoff0[3];
#pragma unroll
  for (int dx = 0; dx < 3; ++dx) {
    int p = p0 + dx;
    hoff0[dx] = (p * 4 + (oct ^ ((p >> 1) & 3))) * 16;  // bytes
  }

  // Prologue: stage buf0 (7 instrs) then iter-0 taps 0-1 A-frags (8 loads);
  // vmcnt(8) -> staging retired, A-prologue stays in flight.
#pragma unroll
  for (int s = 0; s < 7; ++s) stage1(s, 0, 0);
  bf16x8 af[2][4];
#pragma unroll
  for (int t = 0; t < 2; ++t)
#pragma unroll
    for (int mt = 0; mt < 4; ++mt)
      af[t][mt] = *(const bf16x8*)(Alane + (size_t)t * 16384 + mt * 512);
  asm volatile("s_waitcnt vmcnt(8)" ::: "memory");
  __builtin_amdgcn_sched_barrier(0);
  __builtin_amdgcn_s_barrier();

  for (int it = 0; it < 32; ++it) {
    const ushort* Ait = Alane + (size_t)it * (9 * 16384);
    const ushort* An  = Ait + (size_t)(9 * 16384);
    const char* hb0 = (const char*)(halo + (size_t)(it & 1) * SLOTS2 * 8);
    const int nbuf = (it + 1) & 1;
    const int nci  = (it + 1) * 32;
    const bool more = (it < 31);

#pragma unroll
    for (int t = 0; t < 9; ++t) {
      const int r = t / 3, dx = t % 3;
      bf16x8 bfr[8];
#pragma unroll
      for (int nt = 0; nt < 8; ++nt)
        bfr[nt] = *(const bf16x8*)(hb0 + r * (ROWC2 * 16) + nt * 1024 + hoff0[dx]);
      if (t < 7 && more) stage1(t, nbuf, nci);
      __builtin_amdgcn_s_barrier();
      asm volatile("s_waitcnt lgkmcnt(0)" ::: "memory");
      __builtin_amdgcn_sched_barrier(0);
      __builtin_amdgcn_s_setprio(1);
#pragma unroll
      for (int nt = 0; nt < 8; ++nt)
#pragma unroll
        for (int mt = 0; mt < 4; ++mt)
          acc[mt][nt] = __builtin_amdgcn_mfma_f32_16x16x32_bf16(
              af[t & 1][mt], bfr[nt], acc[mt][nt], 0, 0, 0);
      __builtin_amdgcn_s_setprio(0);
      if (t < 7) {
#pragma unroll
        for (int mt = 0; mt < 4; ++mt)
          af[t & 1][mt] = *(const bf16x8*)(Ait + (size_t)(t + 2) * 16384 + mt * 512);
      } else if (t == 8 && more) {
#pragma unroll
        for (int mt = 0; mt < 4; ++mt)
          af[0][mt] = *(const bf16x8*)(An + mt * 512);
#pragma unroll
        for (int mt = 0; mt < 4; ++mt)
          af[1][mt] = *(const bf16x8*)(An + 16384 + mt * 512);
      }
      if (t == 8) {
        asm volatile("s_waitcnt vmcnt(8)" ::: "memory");
        __builtin_amdgcn_sched_barrier(0);
      }
      __builtin_amdgcn_s_barrier();
    }
  }

  // Epilogue: BN + ReLU, fp32 NCHW out.
  const int q4 = lane >> 4, col = lane & 15;
  float* Outf = out + (size_t)z * 512 * NPIX;
#pragma unroll
  for (int mt = 0; mt < 4; ++mt)
#pragma unroll
    for (int r = 0; r < 4; ++r) {
      int m = m0 + wm + mt * 16 + q4 * 4 + r;
      float s  = bn[m] * rsqrtf(bn[3 * 512 + m] + EPS);
      float bo = bn[512 + m] - bn[2 * 512 + m] * s;
      float* rowp = Outf + (size_t)m * NPIX + h * 256 + wnp;
#pragma unroll
      for (int nt = 0; nt < 8; ++nt)
        rowp[nt * 16 + col] = fmaxf(acc[mt][nt][r] * s + bo, 0.f);
    }
}

// ---------------------------------------------------------------------------
// Small GEMM for the k/v path: 4-way K-split + LDS reduce.
// ---------------------------------------------------------------------------
__global__ __launch_bounds__(256) void small_gemm_kernel(
    const float* __restrict__ Wm, const float* __restrict__ X,
    const float* __restrict__ bn, float* __restrict__ Y,
    int CO, int CI, int KC) {
  int co = blockIdx.x, b = blockIdx.y;
  int q = threadIdx.x >> 6, kc = threadIdx.x & 63;
  __shared__ float part[3][24];
  const float* Xb = X + (size_t)b * CI * KC;
  const float* Wr = Wm + (size_t)co * CI;
  float acc = 0.f;
  int cq = CI >> 2;
  if (kc < KC) {
    for (int c = q * cq; c < (q + 1) * cq; ++c)
      acc += Wr[c] * Xb[(size_t)c * KC + kc];
  }
  if (q > 0 && kc < KC) part[q - 1][kc] = acc;
  __syncthreads();
  if (q == 0 && kc < KC) {
    acc += part[0][kc] + part[1][kc] + part[2][kc];
    float s  = bn[co] * rsqrtf(bn[3 * CO + co] + EPS);
    float bs = bn[CO + co] - bn[2 * CO + co] * s;
    Y[((size_t)b * CO + co) * KC + kc] = fmaxf(acc * s + bs, 0.f);
  }
}

// ---------------------------------------------------------------------------
// Attention: qT/ctxT in [pixel][256ch] bf16; k/v fp32 staged in LDS.
// ---------------------------------------------------------------------------
__global__ __launch_bounds__(256) void attention_kernel(
    const ushort* __restrict__ qT, const float* __restrict__ Kp,
    const float* __restrict__ Vp, ushort* __restrict__ ctxT) {
  int b = blockIdx.y;
  int pix = blockIdx.x * 256 + threadIdx.x;
  __shared__ float ks[256][19], vs[256][19];
  for (int idx = threadIdx.x; idx < 256 * 19; idx += 256) {
    int c = idx / 19, kk = idx % 19;
    ks[c][kk] = Kp[((size_t)b * 256 + c) * 19 + kk];
    vs[c][kk] = Vp[((size_t)b * 256 + c) * 19 + kk];
  }
  __syncthreads();

  const ushort* qrow = qT + ((size_t)b * NPIX + pix) * 256;
  float sim[19];
#pragma unroll
  for (int kk = 0; kk < 19; ++kk) sim[kk] = 0.f;
  for (int c0 = 0; c0 < 256; c0 += 8) {
    uint4 raw = *(const uint4*)(qrow + c0);
    float qf[8] = {bf2f((ushort)(raw.x & 0xffff)), bf2f((ushort)(raw.x >> 16)),
                   bf2f((ushort)(raw.y & 0xffff)), bf2f((ushort)(raw.y >> 16)),
                   bf2f((ushort)(raw.z & 0xffff)), bf2f((ushort)(raw.z >> 16)),
                   bf2f((ushort)(raw.w & 0xffff)), bf2f((ushort)(raw.w >> 16))};
#pragma unroll
    for (int j = 0; j < 8; ++j)
#pragma unroll
      for (int kk = 0; kk < 19; ++kk) sim[kk] += qf[j] * ks[c0 + j][kk];
  }
  const float scale = 0.0625f;
  float mx = -1e30f;
#pragma unroll
  for (int kk = 0; kk < 19; ++kk) { sim[kk] *= scale; mx = fmaxf(mx, sim[kk]); }
  float denom = 0.f;
#pragma unroll
  for (int kk = 0; kk < 19; ++kk) { sim[kk] = __expf(sim[kk] - mx); denom += sim[kk]; }
  float inv = 1.f / denom;
#pragma unroll
  for (int kk = 0; kk < 19; ++kk) sim[kk] *= inv;

  ushort* crow = ctxT + ((size_t)b * NPIX + pix) * 256;
  for (int c0 = 0; c0 < 256; c0 += 8) {
    uint32_t o[4];
#pragma unroll
    for (int j = 0; j < 4; ++j) {
      float v0 = 0.f, v1 = 0.f;
#pragma unroll
      for (int kk = 0; kk < 19; ++kk) {
        v0 += sim[kk] * vs[c0 + j * 2][kk];
        v1 += sim[kk] * vs[c0 + j * 2 + 1][kk];
      }
      o[j] = (uint32_t)f2bf(v0) | ((uint32_t)f2bf(v1) << 16);
    }
    *(uint4*)(crow + c0) = make_uint4(o[0], o[1], o[2], o[3]);
  }
}

// ---------------------------------------------------------------------------
// Transpose x (fp32 [b][512][HW]) into cat_pad (bf16 [b][p][1024], ch 512..1023)
// ---------------------------------------------------------------------------
__global__ __launch_bounds__(256) void transpose_x_kernel(
    const float* __restrict__ x, ushort* __restrict__ cat) {
  int b = blockIdx.z, ci0 = blockIdx.y * 64, n0 = blockIdx.x * 64;
  __shared__ float t[64][65];
  const float* xb = x + ((size_t)b * 512 + ci0) * NPIX + n0;
  for (int i = 0; i < 16; ++i) {
    int idx = i * 256 + threadIdx.x;
    int c = idx >> 6, w = idx & 63;
    t[c][w] = xb[(size_t)c * NPIX + w];
  }
  __syncthreads();
  int h = n0 >> 8, w0 = n0 & 255;
  size_t pbase = ((size_t)b * PADROWS + (size_t)(h + 1) * PADW + (w0 + 1)) * 1024 + 512 + ci0;
  for (int i = 0; i < 16; ++i) {
    int idx = i * 256 + threadIdx.x;
    int n = idx >> 6, c = idx & 63;
    cat[pbase + (size_t)n * 1024 + c] = f2bf(t[c][n]);
  }
}

// ---------------------------------------------------------------------------
// Zero only the pad border ring of cat.
// ---------------------------------------------------------------------------
__global__ __launch_bounds__(256) void zero_border_kernel(ushort* __restrict__ cat) {
  int b = blockIdx.y, i = blockIdx.x;
  int row, col;
  if (i < 258)      { row = 0;            col = i; }
  else if (i < 516) { row = 129;          col = i - 258; }
  else if (i < 644) { row = i - 516 + 1;  col = 0; }
  else              { row = i - 644 + 1;  col = 257; }
  size_t base = ((size_t)b * PADROWS + (size_t)row * PADW + col) * 1024 +
                (size_t)threadIdx.x * 4;
  *(ushort4*)(cat + base) = make_ushort4(0, 0, 0, 0);
}

// ---------------------------------------------------------------------------
// Weight conversions
// ---------------------------------------------------------------------------
__global__ void convert_w_kernel(const float* __restrict__ in, ushort* __restrict__ out, int n) {
  int i = blockIdx.x * 256 + threadIdx.x;
  if (i < n) out[i] = f2bf(in[i]);
}
// Repack wbot (co,ci,ky,kx) fp32 -> W2 bf16 [ci_chunk 32][tap 9][co 512][32 ci]
__global__ void repack_conv_w_kernel(const float* __restrict__ wbot, ushort* __restrict__ Wrb) {
  int idx = blockIdx.x * 256 + threadIdx.x;
  if (idx >= 512 * 9216) return;
  int ci_in = idx & 31;
  int r  = idx >> 5;
  int co = r & 511;
  int tt = r >> 9;
  int t = tt % 9, chunk = tt / 9;
  Wrb[idx] = f2bf(wbot[((size_t)co * 1024 + chunk * 32 + ci_in) * 9 + t]);
}

// ---------------------------------------------------------------------------
extern "C" void kernel_launch(void* const* d_in, const int* in_sizes, int n_in,
                              void* d_out, int out_size, void* d_ws, size_t ws_size,
                              hipStream_t stream) {
  const float* x     = (const float*)d_in[0];
  const float* proxy = (const float*)d_in[1];
  const float* wq1   = (const float*)d_in[2];
  const float* bnq1  = (const float*)d_in[3];
  const float* wq2   = (const float*)d_in[4];
  const float* bnq2  = (const float*)d_in[5];
  const float* wk1   = (const float*)d_in[6];
  const float* bnk1  = (const float*)d_in[7];
  const float* wk2   = (const float*)d_in[8];
  const float* bnk2  = (const float*)d_in[9];
  const float* wv    = (const float*)d_in[10];
  const float* bnv   = (const float*)d_in[11];
  const float* wout  = (const float*)d_in[12];
  const float* bnout = (const float*)d_in[13];
  const float* wbot  = (const float*)d_in[14];
  const float* bnbot = (const float*)d_in[15];
  float* out = (float*)d_out;

  const int B = 2, C = 512, CK = 256, KC = 19;
  char* ws = (char*)d_ws;
  ushort* cat  = (ushort*)ws;
  ushort* bufA = (ushort*)(ws + 137379840);                // q1T, later ctxT (32 MiB)
  ushort* bufB = (ushort*)(ws + 137379840 + 33554432);     // qT (32 MiB)
  ushort* Wrb  = (ushort*)(ws + 204488704);                // 9 MiB
  ushort* wq1b = (ushort*)(ws + 213925888);
  ushort* wq2b = (ushort*)(ws + 214188032);
  ushort* woutb= (ushort*)(ws + 214319104);
  float*  k1   = (float*)(ws + 214581248);
  float*  k2   = k1 + (size_t)B * CK * KC;
  float*  vv   = k2 + (size_t)B * CK * KC;

  zero_border_kernel<<<dim3(772, B), 256, 0, stream>>>(cat);

  convert_w_kernel<<<(CK * C + 255) / 256, 256, 0, stream>>>(wq1, wq1b, CK * C);
  convert_w_kernel<<<(CK * CK + 255) / 256, 256, 0, stream>>>(wq2, wq2b, CK * CK);
  convert_w_kernel<<<(C * CK + 255) / 256, 256, 0, stream>>>(wout, woutb, C * CK);
  repack_conv_w_kernel<<<(512 * 9216 + 255) / 256, 256, 0, stream>>>(wbot, Wrb);

  small_gemm_kernel<<<dim3(CK, B), 256, 0, stream>>>(wk1, proxy, bnk1, k1, CK, C, KC);
  small_gemm_kernel<<<dim3(CK, B), 256, 0, stream>>>(wk2, k1, bnk2, k2, CK, CK, KC);
  small_gemm_kernel<<<dim3(CK, B), 256, 0, stream>>>(wv, proxy, bnv, vv, CK, C, KC);

  transpose_x_kernel<<<dim3(NPIX / 64, 8, B), 256, 0, stream>>>(x, cat);

  const long padStride = (long)PADROWS * 1024;
  const long nckStride = (long)NPIX * 256;

  mfma_gemm<1, 0><<<dim3(NPIX / 128, 2, B), 256, 0, stream>>>(
      wq1b, cat, bnq1, bufA, 256, 512, 1024, 512, padStride, 256, nckStride);
  mfma_gemm<0, 0><<<dim3(NPIX / 128, 2, B), 256, 0, stream>>>(
      wq2b, bufA, bnq2, bufB, 256, 256, 256, 0, nckStride, 256, nckStride);

  attention_kernel<<<dim3(NPIX / 256, B), 256, 0, stream>>>(bufB, k2, vv, bufA);

  mfma_gemm<0, 1><<<dim3(NPIX / 128, 4, B), 256, 0, stream>>>(
      woutb, bufA, bnout, cat, 512, 256, 256, 0, nckStride, 1024, padStride);

  // conv3x3: 256co x 256px tile, 8 waves; grid.x = h*2 + m (XCD pins m-tile)
  conv3x3_mfma<<<dim3(256, 1, B), 512, 0, stream>>>(Wrb, cat, bnbot, out);
}